// Round 8
// baseline (382.615 us; speedup 1.0000x reference)
//
#include <hip/hip_runtime.h>
#include <math.h>

// ---------------- problem constants ----------------
#define PP    25
#define CCH   640
#define NCOL  5000
#define VSTRIDE 6400         // 200 items * 32 padded positions
#define SCALE_INV 0.17677669529663687f   // 1/sqrt(32)

// ---------------- workspace float offsets ----------------
#define XTB_OFF   0L         // bf16 [5000][640]  (shortcuts + proj B operand)
#define WB_OFF    1600000L   // bf16 [3][640][640]
#define PROJB_OFF 2214400L   // bf16 [2][5000][640]  (Q,K only)
#define VT_OFF    5414400L   // bf16 [640][6400]     (V channel-major, padded)
#define MMD_OFF   7462400L   // [750]

typedef __attribute__((ext_vector_type(8)))  short          s16x8;
typedef __attribute__((ext_vector_type(8)))  unsigned short u16x8;
typedef __attribute__((ext_vector_type(4)))  unsigned short u16x4;
typedef __attribute__((ext_vector_type(16))) float          f32x16;

__device__ inline unsigned short f2bf(float x) {
  unsigned u = __float_as_uint(x);
  unsigned r = u + 0x7fff + ((u >> 16) & 1);   // RNE
  return (unsigned short)(r >> 16);
}
__device__ inline float bf2f(unsigned short b) {
  return __uint_as_float(((unsigned)b) << 16);
}
__device__ inline unsigned cvtpk(float lo, float hi) {
  unsigned r;
  asm("v_cvt_pk_bf16_f32 %0, %1, %2" : "=v"(r) : "v"(lo), "v"(hi));
  return r;
}

// =====================================================================
// Kernel T: build XTB bf16 [col][c]
// =====================================================================
__global__ __launch_bounds__(256) void t_kernel(const float* __restrict__ sup,
                                                const float* __restrict__ qry,
                                                unsigned short* __restrict__ XTB) {
  __shared__ float lds[16000];
  int item = blockIdx.x;
  const float* src = (item < 50) ? (sup + item * 16000) : (qry + (item - 50) * 16000);
  int tid = threadIdx.x;
  for (int e = tid * 4; e < 16000; e += 1024)
    *(float4*)&lds[e] = *(const float4*)&src[e];
  __syncthreads();
  int ibase = item * PP;
  for (int e = tid * 4; e < 16000; e += 1024) {
    int p = e / CCH, c = e - p * CCH;
    u16x4 b;
    b.x = f2bf(lds[(c + 0) * PP + p]);
    b.y = f2bf(lds[(c + 1) * PP + p]);
    b.z = f2bf(lds[(c + 2) * PP + p]);
    b.w = f2bf(lds[(c + 3) * PP + p]);
    *(u16x4*)&XTB[(long)(ibase + p) * CCH + c] = b;
  }
}

// =====================================================================
// Kernel W: convert Wq/Wk/Wv fp32 -> bf16 WB[3][640][640]
// =====================================================================
__global__ __launch_bounds__(256) void w_kernel(const float* __restrict__ Wq,
                                                const float* __restrict__ Wk,
                                                const float* __restrict__ Wv,
                                                unsigned short* __restrict__ WB) {
  long base = ((long)blockIdx.x * 256 + threadIdx.x) * 8;
  int m = (int)(base / 409600L);
  long off = base - (long)m * 409600L;
  const float* W = (m == 0) ? Wq : ((m == 1) ? Wk : Wv);
  float4 a = *(const float4*)&W[off];
  float4 c = *(const float4*)&W[off + 4];
  u16x8 v;
  v[0] = f2bf(a.x); v[1] = f2bf(a.y); v[2] = f2bf(a.z); v[3] = f2bf(a.w);
  v[4] = f2bf(c.x); v[5] = f2bf(c.y); v[6] = f2bf(c.z); v[7] = f2bf(c.w);
  *(u16x8*)&WB[base] = v;
}

// =====================================================================
// Kernel A: MFMA bf16 projections. Q,K -> projB [col][o]; V -> VT [o][item*32+p]
// =====================================================================
__global__ __launch_bounds__(512) void proj_kernel(const unsigned short* __restrict__ WB,
                                                   const unsigned short* __restrict__ XTB,
                                                   unsigned short* __restrict__ projB,
                                                   unsigned short* __restrict__ VT) {
  __shared__ __align__(16) unsigned short At[128 * 64];
  __shared__ __align__(16) unsigned short Bt[128 * 64];
  int m = blockIdx.z;
  int ctile = blockIdx.x * 128, otile = blockIdx.y * 128;
  const unsigned short* Wsrc = WB + (long)m * 409600L;
  int tid = threadIdx.x;
  int w = tid >> 6, lane = tid & 63;
  int wr = w >> 2, wc = w & 3;
  int lr = lane & 31, ksel = lane >> 5;
  int sr = tid >> 2, sg = (tid & 3) * 2;

  f32x16 acc[2];
#pragma unroll
  for (int a = 0; a < 2; a++)
#pragma unroll
    for (int e = 0; e < 16; e++) acc[a][e] = 0.f;

  int bcol = ctile + sr;
  const unsigned short* asrc = Wsrc + (long)(otile + sr) * CCH + sg * 8;
  const unsigned short* bsrc = XTB + (long)bcol * CCH + sg * 8;

  u16x8 pa[2], pb[2];
#pragma unroll
  for (int gi = 0; gi < 2; gi++) {
    pa[gi] = *(const u16x8*)&asrc[gi * 8];
    if (bcol < NCOL) pb[gi] = *(const u16x8*)&bsrc[gi * 8];
    else { u16x8 z; for (int e = 0; e < 8; e++) z[e] = 0; pb[gi] = z; }
  }

  for (int kc = 0; kc < 10; kc++) {
    __syncthreads();
#pragma unroll
    for (int gi = 0; gi < 2; gi++) {
      int g = sg + gi;
      *(u16x8*)&At[sr * 64 + ((g ^ (sr & 7)) << 3)] = pa[gi];
      *(u16x8*)&Bt[sr * 64 + ((g ^ (sr & 7)) << 3)] = pb[gi];
    }
    if (kc < 9) {
      const unsigned short* an = asrc + (kc + 1) * 64;
      const unsigned short* bn = bsrc + (kc + 1) * 64;
#pragma unroll
      for (int gi = 0; gi < 2; gi++) {
        pa[gi] = *(const u16x8*)&an[gi * 8];
        if (bcol < NCOL) pb[gi] = *(const u16x8*)&bn[gi * 8];
      }
    }
    __syncthreads();
#pragma unroll
    for (int ks = 0; ks < 4; ks++) {
      int gk = ks * 2 + ksel;
      s16x8 bf1;
      {
        int R = wc * 32 + lr;
        bf1 = *(const s16x8*)&Bt[R * 64 + ((gk ^ (R & 7)) << 3)];
      }
#pragma unroll
      for (int a = 0; a < 2; a++) {
        int R = (wr + 2 * a) * 32 + lr;
        s16x8 af = *(const s16x8*)&At[R * 64 + ((gk ^ (R & 7)) << 3)];
        acc[a] = __builtin_amdgcn_mfma_f32_32x32x16_bf16(af, bf1, acc[a], 0, 0, 0);
      }
    }
  }

  int col = ctile + wc * 32 + lr;
  if (col < NCOL) {
    if (m < 2) {
      unsigned short* out = projB + (long)m * NCOL * CCH;
#pragma unroll
      for (int a = 0; a < 2; a++) {
        int obase = otile + (wr + 2 * a) * 32 + 4 * ksel;
#pragma unroll
        for (int g2 = 0; g2 < 4; g2++) {
          u16x4 v;
          v.x = f2bf(acc[a][g2 * 4 + 0]);
          v.y = f2bf(acc[a][g2 * 4 + 1]);
          v.z = f2bf(acc[a][g2 * 4 + 2]);
          v.w = f2bf(acc[a][g2 * 4 + 3]);
          *(u16x4*)&out[(long)col * CCH + obase + g2 * 8] = v;
        }
      }
    } else {
      // V: channel-major padded layout VT[o][item*32 + p]
      int item = col / 25, p = col - item * 25;
#pragma unroll
      for (int a = 0; a < 2; a++) {
        int obase = otile + (wr + 2 * a) * 32 + 4 * ksel;
#pragma unroll
        for (int g2 = 0; g2 < 4; g2++)
#pragma unroll
          for (int i = 0; i < 4; i++) {
            int o = obase + g2 * 8 + i;
            VT[(long)o * VSTRIDE + item * 32 + p] = f2bf(acc[a][g2 * 4 + i]);
          }
      }
    }
  }
}

// =====================================================================
// Kernel B+C fused: attention -> LDS feature tile -> Gram accumulate.
// One block per (pair,way); 8 waves; kc in [0,5) covers 4 heads x 2 sides.
// Tile 256x128 bf16, 16-granule XOR swizzle ((g ^ (row&15))<<3).
// Row 250 = ones (row-sum harvest), 251..255 = 0.
// =====================================================================
__global__ __launch_bounds__(512, 2) void attgram_kernel(
    const unsigned short* __restrict__ projB,
    const unsigned short* __restrict__ VT,
    const unsigned short* __restrict__ XTB,
    float* __restrict__ mmd) {
  __shared__ __align__(16) unsigned short tile[256 * 128];
  __shared__ float sums[256], nrmsq[256], meanv[256], nrmv[256];
  __shared__ float red[24];
  int tid = threadIdx.x, wid = tid >> 6, lane = tid & 63;
  int lr = lane & 31, hf = lane >> 5;
  int rclamp = lr > 24 ? 24 : lr;
  int pw = blockIdx.x;
  int pair = pw / 5, way = pw - pair * 5;
  int b = pair / 75;
  int qcol = (50 + pair) * PP;
  int qitem = 50 + pair;
  int sitem0 = b * 25 + way * 5;
  const unsigned short* Qp = projB;
  const unsigned short* Kp = projB + (long)NCOL * CCH;

  int side = wid & 1, hsub = wid >> 1;   // attention unit assignment
  int wr = wid >> 2, wc = wid & 3;       // gram tile assignment

  f32x16 acc[4][2];
#pragma unroll
  for (int a = 0; a < 4; a++)
#pragma unroll
    for (int b2 = 0; b2 < 2; b2++)
#pragma unroll
      for (int e = 0; e < 16; e++) acc[a][b2][e] = 0.f;

  for (int kc = 0; kc < 5; kc++) {
    int h = kc * 4 + hsub;
    int ho = h * 32;
    __syncthreads();   // previous gram phase done reading tile
    // rows 250..255: ones row + zeros
    if (tid < 96) {
      int rr = 250 + (tid >> 4), g = tid & 15;
      unsigned short val = (rr == 250) ? (unsigned short)0x3F80 : (unsigned short)0;
      u16x8 v;
#pragma unroll
      for (int e = 0; e < 8; e++) v[e] = val;
      *(u16x8*)&tile[rr * 128 + ((g ^ (rr & 15)) << 3)] = v;
    }

    // ---- attention phase for unit (h, side) ----
    auto ldfrag = [&](const unsigned short* src, int col0, int ks) -> s16x8 {
      return *(const s16x8*)&src[(long)(col0 + rclamp) * CCH + ho + ks * 16 + hf * 8];
    };
    auto ldvfrag = [&](int item, int ks) -> s16x8 {
      return *(const s16x8*)&VT[(long)(ho + lr) * VSTRIDE + item * 32 + ks * 16 + hf * 8];
    };

    s16x8 fA0, fA1, fB0, fB1, fV0, fV1;
    if (side == 0) {               // Q = query item fixed
      fB0 = ldfrag(Qp, qcol, 0); fB1 = ldfrag(Qp, qcol, 1);
    } else {                       // K/V = query item fixed
      fA0 = ldfrag(Kp, qcol, 0); fA1 = ldfrag(Kp, qcol, 1);
      fV0 = ldvfrag(qitem, 0);   fV1 = ldvfrag(qitem, 1);
    }

    for (int shot = 0; shot < 5; shot++) {
      int sitem = sitem0 + shot, scol = sitem * PP;
      s16x8 A0, A1, B0, B1, V0, V1;
      if (side == 0) {
        A0 = ldfrag(Kp, scol, 0); A1 = ldfrag(Kp, scol, 1);
        B0 = fB0; B1 = fB1;
        V0 = ldvfrag(sitem, 0);   V1 = ldvfrag(sitem, 1);
      } else {
        A0 = fA0; A1 = fA1;
        B0 = ldfrag(Qp, scol, 0); B1 = ldfrag(Qp, scol, 1);
        V0 = fV0; V1 = fV1;
      }
      // S^T = K·Q^T : D[m][q], q = lr
      f32x16 s;
#pragma unroll
      for (int e = 0; e < 16; e++) s[e] = 0.f;
      s = __builtin_amdgcn_mfma_f32_32x32x16_bf16(A0, B0, s, 0, 0, 0);
      s = __builtin_amdgcn_mfma_f32_32x32x16_bf16(A1, B1, s, 0, 0, 0);
      // softmax over m for this lane's q
      float pv[16];
      float mx = -1e30f;
#pragma unroll
      for (int rg = 0; rg < 16; rg++) {
        int mm = (rg & 3) + 8 * (rg >> 2) + 4 * hf;
        float v = (mm < 25) ? s[rg] : -1e30f;
        pv[rg] = v;
        mx = fmaxf(mx, v);
      }
      mx = fmaxf(mx, __shfl_xor(mx, 32));
      float sum = 0.f;
#pragma unroll
      for (int rg = 0; rg < 16; rg++) {
        float e = __expf((pv[rg] - mx) * SCALE_INV);
        pv[rg] = e;
        sum += e;
      }
      sum += __shfl_xor(sum, 32);
      float rinv = 1.f / sum;
#pragma unroll
      for (int rg = 0; rg < 16; rg++) pv[rg] *= rinv;
      // pack P A-frags (half-swap) via v_cvt_pk_bf16_f32
      union { unsigned u[4]; s16x8 v; } P0u, P1u;
      {
        float ex[8], fr[8];
#pragma unroll
        for (int r = 0; r < 8; r++) ex[r] = __shfl_xor(pv[r], 32);
#pragma unroll
        for (int j = 0; j < 4; j++) {
          fr[j]     = hf ? ex[4 + j] : pv[j];
          fr[4 + j] = hf ? pv[4 + j] : ex[j];
        }
#pragma unroll
        for (int j = 0; j < 4; j++) P0u.u[j] = cvtpk(fr[2 * j], fr[2 * j + 1]);
#pragma unroll
        for (int r = 0; r < 8; r++) ex[r] = __shfl_xor(pv[8 + r], 32);
#pragma unroll
        for (int j = 0; j < 4; j++) {
          fr[j]     = hf ? ex[4 + j] : pv[8 + j];
          fr[4 + j] = hf ? pv[12 + j] : ex[j];
        }
#pragma unroll
        for (int j = 0; j < 4; j++) P1u.u[j] = cvtpk(fr[2 * j], fr[2 * j + 1]);
      }
      // O = P·V
      f32x16 o;
#pragma unroll
      for (int e = 0; e < 16; e++) o[e] = 0.f;
      o = __builtin_amdgcn_mfma_f32_32x32x16_bf16(P0u.v, V0, o, 0, 0, 0);
      o = __builtin_amdgcn_mfma_f32_32x32x16_bf16(P1u.v, V1, o, 0, 0, 0);
      // shortcut + bf16 -> swizzled LDS tile
      int scrow = side ? qcol : scol;
      int rowbase = (side ? 125 : 0) + shot * 25;
      int cc = hsub * 32 + lr;
#pragma unroll
      for (int i = 0; i < 8; i++) {
        int rg0 = 2 * i;
        int q0 = (rg0 & 3) + 8 * (rg0 >> 2) + 4 * hf;
        int q1 = q0 + 1;
        int q0c = q0 > 24 ? 24 : q0, q1c = q1 > 24 ? 24 : q1;
        float sc0 = bf2f(XTB[(long)(scrow + q0c) * CCH + ho + lr]);
        float sc1 = bf2f(XTB[(long)(scrow + q1c) * CCH + ho + lr]);
        unsigned u = cvtpk(o[rg0] + sc0, o[rg0 + 1] + sc1);
        if (q0 < 25) {
          int row = rowbase + q0;
          tile[row * 128 + (((cc >> 3) ^ (row & 15)) << 3) + (cc & 7)] = (unsigned short)u;
        }
        if (q1 < 25) {
          int row = rowbase + q1;
          tile[row * 128 + (((cc >> 3) ^ (row & 15)) << 3) + (cc & 7)] = (unsigned short)(u >> 16);
        }
      }
    }
    __syncthreads();   // tile ready for gram
    // ---- gram accumulate over this 128-ch chunk ----
#pragma unroll
    for (int ks = 0; ks < 8; ks++) {
      int gk = ks * 2 + hf;
      s16x8 af[4], bfv[2];
#pragma unroll
      for (int a = 0; a < 4; a++) {
        int R = (wr + 2 * a) * 32 + lr;
        af[a] = *(const s16x8*)&tile[R * 128 + ((gk ^ (R & 15)) << 3)];
      }
#pragma unroll
      for (int b2 = 0; b2 < 2; b2++) {
        int R = (wc + 4 * b2) * 32 + lr;
        bfv[b2] = *(const s16x8*)&tile[R * 128 + ((gk ^ (R & 15)) << 3)];
      }
#pragma unroll
      for (int a = 0; a < 4; a++)
#pragma unroll
        for (int b2 = 0; b2 < 2; b2++)
          acc[a][b2] = __builtin_amdgcn_mfma_f32_32x32x16_bf16(af[a], bfv[b2], acc[a][b2], 0, 0, 0);
    }
  }

  // ---- harvest row sums (col 250) and squared norms (diagonal) ----
#pragma unroll
  for (int a = 0; a < 4; a++) {
    int ti = wr + 2 * a;
#pragma unroll
    for (int b2 = 0; b2 < 2; b2++) {
      int tj = wc + 4 * b2;
      int col = tj * 32 + lr;
      if (col == 250) {
#pragma unroll
        for (int rg = 0; rg < 16; rg++) {
          int row = ti * 32 + (rg & 3) + 8 * (rg >> 2) + 4 * hf;
          if (row < 250) sums[row] = acc[a][b2][rg];
        }
      }
      if (ti == tj) {
#pragma unroll
        for (int rg = 0; rg < 16; rg++) {
          int row = ti * 32 + (rg & 3) + 8 * (rg >> 2) + 4 * hf;
          if (row == col && row < 250) nrmsq[row] = acc[a][b2][rg];
        }
      }
    }
  }
  __syncthreads();
  if (tid < 250) {
    float s0 = sums[tid];
    float m = s0 * (1.f / 640.f);
    meanv[tid] = m;
    nrmv[tid] = nrmsq[tid] - s0 * m;
  }
  __syncthreads();

  // ---- epilogue: d2 -> 5-term gaussian kernel -> region sums ----
  float s_ss = 0.f, s_qq = 0.f, s_x = 0.f;
#pragma unroll
  for (int a = 0; a < 4; a++) {
    int ti = wr + 2 * a;
#pragma unroll
    for (int b2 = 0; b2 < 2; b2++) {
      int tj = wc + 4 * b2;
      int col = tj * 32 + lr;
#pragma unroll
      for (int rg = 0; rg < 16; rg++) {
        int row = ti * 32 + (rg & 3) + 8 * (rg >> 2) + 4 * hf;
        if (row < 250 && col < 250) {
          float d2 = nrmv[row] + nrmv[col] - 2.f * acc[a][b2][rg]
                   + 1280.f * meanv[row] * meanv[col];
          d2 = fmaxf(d2, 0.f);
          float e = __expf(-0.125f * d2);
          float e2 = e * e, e4 = e2 * e2, e8 = e4 * e4, e16 = e8 * e8;
          float kv = e + e2 + e4 + e8 + e16;
          bool rs = row < 125, cs = col < 125;
          if (rs && cs)        { if (row != col) s_ss += kv; }
          else if (!rs && !cs) { if (row != col) s_qq += kv; }
          else                 s_x += kv;   // Kqs + Ksq = 2*tot(Kqs)
        }
      }
    }
  }
#pragma unroll
  for (int off = 32; off; off >>= 1) {
    s_ss += __shfl_xor(s_ss, off);
    s_qq += __shfl_xor(s_qq, off);
    s_x  += __shfl_xor(s_x, off);
  }
  if (lane == 0) { red[wid * 3] = s_ss; red[wid * 3 + 1] = s_qq; red[wid * 3 + 2] = s_x; }
  __syncthreads();
  if (tid == 0) {
    float a = 0.f, b2 = 0.f, c = 0.f;
    for (int i = 0; i < 8; i++) { a += red[i * 3]; b2 += red[i * 3 + 1]; c += red[i * 3 + 2]; }
    mmd[pw] = a * (1.f / 15500.f) + b2 * (1.f / 15500.f) - c * (1.f / 15625.f);
  }
}

// =====================================================================
// Kernel D: log-softmax + NLL mean
// =====================================================================
__global__ __launch_bounds__(256) void loss_kernel(const float* __restrict__ mmd,
                                                   const int* __restrict__ qy,
                                                   float* __restrict__ out) {
  __shared__ float red[256];
  int tid = threadIdx.x;
  float val = 0.f;
  if (tid < 150) {
    float l[5];
    float mx = -1e30f;
#pragma unroll
    for (int w = 0; w < 5; w++) {
      l[w] = -mmd[tid * 5 + w] * (1.0f / 12.5f);
      mx = fmaxf(mx, l[w]);
    }
    float sum = 0.f;
#pragma unroll
    for (int w = 0; w < 5; w++) sum += __expf(l[w] - mx);
    float lse = mx + logf(sum);
    int y = qy[tid];
    val = -(l[y] - lse);
  }
  red[tid] = val;
  __syncthreads();
  for (int s = 128; s > 0; s >>= 1) {
    if (tid < s) red[tid] += red[tid + s];
    __syncthreads();
  }
  if (tid == 0) out[0] = red[0] * (1.0f / 150.0f);
}

// =====================================================================
extern "C" void kernel_launch(void* const* d_in, const int* in_sizes, int n_in,
                              void* d_out, int out_size, void* d_ws, size_t ws_size,
                              hipStream_t stream) {
  (void)in_sizes; (void)n_in; (void)out_size; (void)ws_size;
  const float* sup = (const float*)d_in[0];
  const float* qry = (const float*)d_in[2];
  const int* qy = (const int*)d_in[3];
  const float* Wq = (const float*)d_in[4];
  const float* Wk = (const float*)d_in[5];
  const float* Wv = (const float*)d_in[6];
  float* ws = (float*)d_ws;
  unsigned short* XTB = (unsigned short*)(ws + XTB_OFF);
  unsigned short* WB = (unsigned short*)(ws + WB_OFF);
  unsigned short* projB = (unsigned short*)(ws + PROJB_OFF);
  unsigned short* VT = (unsigned short*)(ws + VT_OFF);
  float* mmd = ws + MMD_OFF;
  float* out = (float*)d_out;

  hipLaunchKernelGGL(t_kernel, dim3(200), dim3(256), 0, stream, sup, qry, XTB);
  hipLaunchKernelGGL(w_kernel, dim3(600), dim3(256), 0, stream, Wq, Wk, Wv, WB);
  hipLaunchKernelGGL(proj_kernel, dim3(40, 5, 3), dim3(512), 0, stream, WB, XTB, projB, VT);
  hipLaunchKernelGGL(attgram_kernel, dim3(750), dim3(512), 0, stream, projB, VT, XTB, mmd);
  hipLaunchKernelGGL(loss_kernel, dim3(1), dim3(256), 0, stream, mmd, qy, out);
}

// Round 9
// 381.756 us; speedup vs baseline: 1.0023x; 1.0023x over previous
//
#include <hip/hip_runtime.h>
#include <math.h>

// ---------------- problem constants ----------------
#define PP    25
#define CCH   640
#define NCOL  5000
#define VSTRIDE 6400         // 200 items * 32 padded positions
#define SCALE_INV 0.17677669529663687f   // 1/sqrt(32)

// ---------------- workspace float offsets ----------------
#define XTB_OFF   0L         // bf16 [5000][640]
#define WB_OFF    1600000L   // bf16 [3][640][640]
#define PROJB_OFF 2214400L   // bf16 [2][5000][640]  (Q,K)
#define VT_OFF    5414400L   // bf16 [640][6400]     (V channel-major, padded)
#define MMD_OFF   7462400L   // [750]
#define FEAT_OFF  7463168L   // bf16 head-blocked [way][20][250][32]
#define FEAT_PER_WAY_US 160000L
#define FEAT_PER_PAIR_US 800000L

typedef __attribute__((ext_vector_type(8)))  short          s16x8;
typedef __attribute__((ext_vector_type(8)))  unsigned short u16x8;
typedef __attribute__((ext_vector_type(4)))  unsigned short u16x4;
typedef __attribute__((ext_vector_type(16))) float          f32x16;

__device__ inline unsigned short f2bf(float x) {
  unsigned u = __float_as_uint(x);
  unsigned r = u + 0x7fff + ((u >> 16) & 1);   // RNE
  return (unsigned short)(r >> 16);
}
__device__ inline float bf2f(unsigned short b) {
  return __uint_as_float(((unsigned)b) << 16);
}
__device__ inline unsigned cvtpk(float lo, float hi) {
  unsigned r;
  asm("v_cvt_pk_bf16_f32 %0, %1, %2" : "=v"(r) : "v"(lo), "v"(hi));
  return r;
}

// =====================================================================
// Kernel T: build XTB bf16 [col][c]
// =====================================================================
__global__ __launch_bounds__(256) void t_kernel(const float* __restrict__ sup,
                                                const float* __restrict__ qry,
                                                unsigned short* __restrict__ XTB) {
  __shared__ float lds[16000];
  int item = blockIdx.x;
  const float* src = (item < 50) ? (sup + item * 16000) : (qry + (item - 50) * 16000);
  int tid = threadIdx.x;
  for (int e = tid * 4; e < 16000; e += 1024)
    *(float4*)&lds[e] = *(const float4*)&src[e];
  __syncthreads();
  int ibase = item * PP;
  for (int e = tid * 4; e < 16000; e += 1024) {
    int p = e / CCH, c = e - p * CCH;
    u16x4 b;
    b.x = f2bf(lds[(c + 0) * PP + p]);
    b.y = f2bf(lds[(c + 1) * PP + p]);
    b.z = f2bf(lds[(c + 2) * PP + p]);
    b.w = f2bf(lds[(c + 3) * PP + p]);
    *(u16x4*)&XTB[(long)(ibase + p) * CCH + c] = b;
  }
}

// =====================================================================
// Kernel W: Wq/Wk/Wv fp32 -> bf16
// =====================================================================
__global__ __launch_bounds__(256) void w_kernel(const float* __restrict__ Wq,
                                                const float* __restrict__ Wk,
                                                const float* __restrict__ Wv,
                                                unsigned short* __restrict__ WB) {
  long base = ((long)blockIdx.x * 256 + threadIdx.x) * 8;
  int m = (int)(base / 409600L);
  long off = base - (long)m * 409600L;
  const float* W = (m == 0) ? Wq : ((m == 1) ? Wk : Wv);
  float4 a = *(const float4*)&W[off];
  float4 c = *(const float4*)&W[off + 4];
  u16x8 v;
  v[0] = f2bf(a.x); v[1] = f2bf(a.y); v[2] = f2bf(a.z); v[3] = f2bf(a.w);
  v[4] = f2bf(c.x); v[5] = f2bf(c.y); v[6] = f2bf(c.z); v[7] = f2bf(c.w);
  *(u16x8*)&WB[base] = v;
}

// =====================================================================
// Kernel A: MFMA bf16 projections. Q,K -> projB [col][o]; V -> VT [o][item*32+p]
// =====================================================================
__global__ __launch_bounds__(512) void proj_kernel(const unsigned short* __restrict__ WB,
                                                   const unsigned short* __restrict__ XTB,
                                                   unsigned short* __restrict__ projB,
                                                   unsigned short* __restrict__ VT) {
  __shared__ __align__(16) unsigned short At[128 * 64];
  __shared__ __align__(16) unsigned short Bt[128 * 64];
  int m = blockIdx.z;
  int ctile = blockIdx.x * 128, otile = blockIdx.y * 128;
  const unsigned short* Wsrc = WB + (long)m * 409600L;
  int tid = threadIdx.x;
  int w = tid >> 6, lane = tid & 63;
  int wr = w >> 2, wc = w & 3;
  int lr = lane & 31, ksel = lane >> 5;
  int sr = tid >> 2, sg = (tid & 3) * 2;

  f32x16 acc[2];
#pragma unroll
  for (int a = 0; a < 2; a++)
#pragma unroll
    for (int e = 0; e < 16; e++) acc[a][e] = 0.f;

  int bcol = ctile + sr;
  const unsigned short* asrc = Wsrc + (long)(otile + sr) * CCH + sg * 8;
  const unsigned short* bsrc = XTB + (long)bcol * CCH + sg * 8;

  u16x8 pa[2], pb[2];
#pragma unroll
  for (int gi = 0; gi < 2; gi++) {
    pa[gi] = *(const u16x8*)&asrc[gi * 8];
    if (bcol < NCOL) pb[gi] = *(const u16x8*)&bsrc[gi * 8];
    else { u16x8 z; for (int e = 0; e < 8; e++) z[e] = 0; pb[gi] = z; }
  }

  for (int kc = 0; kc < 10; kc++) {
    __syncthreads();
#pragma unroll
    for (int gi = 0; gi < 2; gi++) {
      int g = sg + gi;
      *(u16x8*)&At[sr * 64 + ((g ^ (sr & 7)) << 3)] = pa[gi];
      *(u16x8*)&Bt[sr * 64 + ((g ^ (sr & 7)) << 3)] = pb[gi];
    }
    if (kc < 9) {
      const unsigned short* an = asrc + (kc + 1) * 64;
      const unsigned short* bn = bsrc + (kc + 1) * 64;
#pragma unroll
      for (int gi = 0; gi < 2; gi++) {
        pa[gi] = *(const u16x8*)&an[gi * 8];
        if (bcol < NCOL) pb[gi] = *(const u16x8*)&bn[gi * 8];
      }
    }
    __syncthreads();
#pragma unroll
    for (int ks = 0; ks < 4; ks++) {
      int gk = ks * 2 + ksel;
      s16x8 bf1;
      {
        int R = wc * 32 + lr;
        bf1 = *(const s16x8*)&Bt[R * 64 + ((gk ^ (R & 7)) << 3)];
      }
#pragma unroll
      for (int a = 0; a < 2; a++) {
        int R = (wr + 2 * a) * 32 + lr;
        s16x8 af = *(const s16x8*)&At[R * 64 + ((gk ^ (R & 7)) << 3)];
        acc[a] = __builtin_amdgcn_mfma_f32_32x32x16_bf16(af, bf1, acc[a], 0, 0, 0);
      }
    }
  }

  int col = ctile + wc * 32 + lr;
  if (col < NCOL) {
    if (m < 2) {
      unsigned short* out = projB + (long)m * NCOL * CCH;
#pragma unroll
      for (int a = 0; a < 2; a++) {
        int obase = otile + (wr + 2 * a) * 32 + 4 * ksel;
#pragma unroll
        for (int g2 = 0; g2 < 4; g2++) {
          u16x4 v;
          v.x = f2bf(acc[a][g2 * 4 + 0]);
          v.y = f2bf(acc[a][g2 * 4 + 1]);
          v.z = f2bf(acc[a][g2 * 4 + 2]);
          v.w = f2bf(acc[a][g2 * 4 + 3]);
          *(u16x4*)&out[(long)col * CCH + obase + g2 * 8] = v;
        }
      }
    } else {
      int item = col / 25, p = col - item * 25;
#pragma unroll
      for (int a = 0; a < 2; a++) {
        int obase = otile + (wr + 2 * a) * 32 + 4 * ksel;
#pragma unroll
        for (int g2 = 0; g2 < 4; g2++)
#pragma unroll
          for (int i = 0; i < 4; i++) {
            int o = obase + g2 * 8 + i;
            VT[(long)o * VSTRIDE + item * 32 + p] = f2bf(acc[a][g2 * 4 + i]);
          }
      }
    }
  }
}

// =====================================================================
// Kernel B: MFMA attention (split, r7 structure). One wave per
// (pair,way,side,head); V-frags from channel-major VT (1x16B load);
// cvt_pk P-pack; side-B shortcut hoisted.
// =====================================================================
__global__ __launch_bounds__(256) void attn_kernel(const unsigned short* __restrict__ projB,
                                                   const unsigned short* __restrict__ VT,
                                                   const unsigned short* __restrict__ XTB,
                                                   unsigned short* __restrict__ feat,
                                                   int chunk_start) {
  int tid = threadIdx.x, wid = tid >> 6, lane = tid & 63;
  int lr = lane & 31, hf = lane >> 5;
  int rclamp = lr > 24 ? 24 : lr;
  int bid = blockIdx.x;
  int pw = bid / 10, grp = bid - pw * 10;
  int unit = grp * 4 + wid;
  int side = unit >= 20 ? 1 : 0;
  int head = unit - side * 20;
  int lpi = pw / 5, way = pw - lpi * 5;
  int pair = chunk_start + lpi;
  int b = pair / 75;
  int qitem = 50 + pair;
  int qcol = qitem * PP;
  int sitem0 = b * 25 + way * 5;
  int ho = head * 32;
  const unsigned short* Qp = projB;
  const unsigned short* Kp = projB + (long)NCOL * CCH;
  unsigned short* fb = feat + (long)pw * FEAT_PER_WAY_US + head * 250 * 32;

  auto ldfrag = [&](const unsigned short* src, int col0, int ks) -> s16x8 {
    return *(const s16x8*)&src[(long)(col0 + rclamp) * CCH + ho + ks * 16 + hf * 8];
  };
  auto ldvfrag = [&](int item, int ks) -> s16x8 {
    return *(const s16x8*)&VT[(long)(ho + lr) * VSTRIDE + item * 32 + ks * 16 + hf * 8];
  };

  s16x8 fA0, fA1, fB0, fB1, fV0, fV1;
  float scv[16];
  if (side == 0) {               // sbq: Q = query item fixed
    fB0 = ldfrag(Qp, qcol, 0); fB1 = ldfrag(Qp, qcol, 1);
  } else {                       // qbs: K/V = query item fixed; shortcut fixed too
    fA0 = ldfrag(Kp, qcol, 0); fA1 = ldfrag(Kp, qcol, 1);
    fV0 = ldvfrag(qitem, 0);   fV1 = ldvfrag(qitem, 1);
#pragma unroll
    for (int rg = 0; rg < 16; rg++) {
      int q = (rg & 3) + 8 * (rg >> 2) + 4 * hf;
      int qc = q > 24 ? 24 : q;
      scv[rg] = bf2f(XTB[(long)(qcol + qc) * CCH + ho + lr]);
    }
  }

  for (int shot = 0; shot < 5; shot++) {
    int sitem = sitem0 + shot, scol = sitem * PP;
    s16x8 A0, A1, B0, B1, V0, V1;
    if (side == 0) {
      A0 = ldfrag(Kp, scol, 0); A1 = ldfrag(Kp, scol, 1);
      B0 = fB0; B1 = fB1;
      V0 = ldvfrag(sitem, 0);   V1 = ldvfrag(sitem, 1);
    } else {
      A0 = fA0; A1 = fA1;
      B0 = ldfrag(Qp, scol, 0); B1 = ldfrag(Qp, scol, 1);
      V0 = fV0; V1 = fV1;
    }
    // S^T = K·Q^T : D[m][q], q = lr
    f32x16 s;
#pragma unroll
    for (int e = 0; e < 16; e++) s[e] = 0.f;
    s = __builtin_amdgcn_mfma_f32_32x32x16_bf16(A0, B0, s, 0, 0, 0);
    s = __builtin_amdgcn_mfma_f32_32x32x16_bf16(A1, B1, s, 0, 0, 0);
    // softmax over m for this lane's q
    float pv[16];
    float mx = -1e30f;
#pragma unroll
    for (int rg = 0; rg < 16; rg++) {
      int mm = (rg & 3) + 8 * (rg >> 2) + 4 * hf;
      float v = (mm < 25) ? s[rg] : -1e30f;
      pv[rg] = v;
      mx = fmaxf(mx, v);
    }
    mx = fmaxf(mx, __shfl_xor(mx, 32));
    float sum = 0.f;
#pragma unroll
    for (int rg = 0; rg < 16; rg++) {
      float e = __expf((pv[rg] - mx) * SCALE_INV);
      pv[rg] = e;
      sum += e;
    }
    sum += __shfl_xor(sum, 32);
    float rinv = 1.f / sum;
#pragma unroll
    for (int rg = 0; rg < 16; rg++) pv[rg] *= rinv;
    // P A-frags (half-swap) via cvt_pk
    union { unsigned u[4]; s16x8 v; } P0u, P1u;
    {
      float ex[8], fr[8];
#pragma unroll
      for (int r = 0; r < 8; r++) ex[r] = __shfl_xor(pv[r], 32);
#pragma unroll
      for (int j = 0; j < 4; j++) {
        fr[j]     = hf ? ex[4 + j] : pv[j];
        fr[4 + j] = hf ? pv[4 + j] : ex[j];
      }
#pragma unroll
      for (int j = 0; j < 4; j++) P0u.u[j] = cvtpk(fr[2 * j], fr[2 * j + 1]);
#pragma unroll
      for (int r = 0; r < 8; r++) ex[r] = __shfl_xor(pv[8 + r], 32);
#pragma unroll
      for (int j = 0; j < 4; j++) {
        fr[j]     = hf ? ex[4 + j] : pv[8 + j];
        fr[4 + j] = hf ? pv[12 + j] : ex[j];
      }
#pragma unroll
      for (int j = 0; j < 4; j++) P1u.u[j] = cvtpk(fr[2 * j], fr[2 * j + 1]);
    }
    // O = P·V
    f32x16 o;
#pragma unroll
    for (int e = 0; e < 16; e++) o[e] = 0.f;
    o = __builtin_amdgcn_mfma_f32_32x32x16_bf16(P0u.v, V0, o, 0, 0, 0);
    o = __builtin_amdgcn_mfma_f32_32x32x16_bf16(P1u.v, V1, o, 0, 0, 0);
    // + shortcut, bf16 store (head-blocked)
    unsigned short* frow = fb + (long)((side ? 125 : 0) + shot * 25) * 32;
#pragma unroll
    for (int rg = 0; rg < 16; rg++) {
      int q = (rg & 3) + 8 * (rg >> 2) + 4 * hf;
      if (q < 25) {
        float sc = side ? scv[rg] : bf2f(XTB[(long)(scol + q) * CCH + ho + lr]);
        frow[q * 32 + lr] = f2bf(o[rg] + sc);
      }
    }
  }
}

// =====================================================================
// Kernel C: MFMA bf16 Gram (rows 0..249 features, row 250 = ones)
// =====================================================================
__device__ inline void gram_load(u16x8* pf, const unsigned short* __restrict__ fb,
                                 int sr, int half, int kc) {
#pragma unroll
  for (int gi = 0; gi < 4; gi++) {
    u16x8 v;
    if (sr < 250) {
      v = *(const u16x8*)&fb[(long)((2 * kc + half) * 250 + sr) * 32 + gi * 8];
    } else if (sr == 250) {
#pragma unroll
      for (int e = 0; e < 8; e++) v[e] = 0x3F80;
    } else {
#pragma unroll
      for (int e = 0; e < 8; e++) v[e] = 0;
    }
    pf[gi] = v;
  }
}

__global__ __launch_bounds__(512) void gram_kernel(const unsigned short* __restrict__ feat,
                                                   float* __restrict__ mmd,
                                                   int chunk_start) {
  __shared__ __align__(16) unsigned short tile[16384];
  __shared__ float sums[256], nrmsq[256], meanv[256], nrmv[256];
  __shared__ float red[24];
  int bid = blockIdx.x;
  const unsigned short* fb = feat + (long)bid * FEAT_PER_WAY_US;
  int tid = threadIdx.x;
  int w = tid >> 6, lane = tid & 63;
  int wr = w >> 2, wc = w & 3;
  int lr = lane & 31, ksel = lane >> 5;
  int sr = tid >> 1, half = tid & 1;

  f32x16 acc[4][2];
#pragma unroll
  for (int a = 0; a < 4; a++)
#pragma unroll
    for (int b2 = 0; b2 < 2; b2++)
#pragma unroll
      for (int e = 0; e < 16; e++) acc[a][b2][e] = 0.f;

  u16x8 pf[4];
  gram_load(pf, fb, sr, half, 0);

  for (int kc = 0; kc < 10; kc++) {
    __syncthreads();
#pragma unroll
    for (int gi = 0; gi < 4; gi++) {
      int g = half * 4 + gi;
      *(u16x8*)&tile[sr * 64 + ((g ^ (sr & 7)) << 3)] = pf[gi];
    }
    if (kc < 9) gram_load(pf, fb, sr, half, kc + 1);
    __syncthreads();
#pragma unroll
    for (int ks = 0; ks < 4; ks++) {
      int gk = ks * 2 + ksel;
      s16x8 af[4], bfv[2];
#pragma unroll
      for (int a = 0; a < 4; a++) {
        int R = (wr + 2 * a) * 32 + lr;
        af[a] = *(const s16x8*)&tile[R * 64 + ((gk ^ (R & 7)) << 3)];
      }
#pragma unroll
      for (int b2 = 0; b2 < 2; b2++) {
        int R = (wc + 4 * b2) * 32 + lr;
        bfv[b2] = *(const s16x8*)&tile[R * 64 + ((gk ^ (R & 7)) << 3)];
      }
#pragma unroll
      for (int a = 0; a < 4; a++)
#pragma unroll
        for (int b2 = 0; b2 < 2; b2++)
          acc[a][b2] = __builtin_amdgcn_mfma_f32_32x32x16_bf16(af[a], bfv[b2], acc[a][b2], 0, 0, 0);
    }
  }

#pragma unroll
  for (int a = 0; a < 4; a++) {
    int ti = wr + 2 * a;
#pragma unroll
    for (int b2 = 0; b2 < 2; b2++) {
      int tj = wc + 4 * b2;
      int col = tj * 32 + lr;
      if (col == 250) {
#pragma unroll
        for (int rg = 0; rg < 16; rg++) {
          int row = ti * 32 + (rg & 3) + 8 * (rg >> 2) + 4 * ksel;
          if (row < 250) sums[row] = acc[a][b2][rg];
        }
      }
      if (ti == tj) {
#pragma unroll
        for (int rg = 0; rg < 16; rg++) {
          int row = ti * 32 + (rg & 3) + 8 * (rg >> 2) + 4 * ksel;
          if (row == col && row < 250) nrmsq[row] = acc[a][b2][rg];
        }
      }
    }
  }
  __syncthreads();
  if (tid < 250) {
    float s0 = sums[tid];
    float m = s0 * (1.f / 640.f);
    meanv[tid] = m;
    nrmv[tid] = nrmsq[tid] - s0 * m;
  }
  __syncthreads();

  float s_ss = 0.f, s_qq = 0.f, s_x = 0.f;
#pragma unroll
  for (int a = 0; a < 4; a++) {
    int ti = wr + 2 * a;
#pragma unroll
    for (int b2 = 0; b2 < 2; b2++) {
      int tj = wc + 4 * b2;
      int col = tj * 32 + lr;
#pragma unroll
      for (int rg = 0; rg < 16; rg++) {
        int row = ti * 32 + (rg & 3) + 8 * (rg >> 2) + 4 * ksel;
        if (row < 250 && col < 250) {
          float d2 = nrmv[row] + nrmv[col] - 2.f * acc[a][b2][rg]
                   + 1280.f * meanv[row] * meanv[col];
          d2 = fmaxf(d2, 0.f);
          float e = __expf(-0.125f * d2);
          float e2 = e * e, e4 = e2 * e2, e8 = e4 * e4, e16 = e8 * e8;
          float kv = e + e2 + e4 + e8 + e16;
          bool rs = row < 125, cs = col < 125;
          if (rs && cs)        { if (row != col) s_ss += kv; }
          else if (!rs && !cs) { if (row != col) s_qq += kv; }
          else                 s_x += kv;
        }
      }
    }
  }
#pragma unroll
  for (int off = 32; off; off >>= 1) {
    s_ss += __shfl_xor(s_ss, off);
    s_qq += __shfl_xor(s_qq, off);
    s_x  += __shfl_xor(s_x, off);
  }
  if (lane == 0) { red[w * 3] = s_ss; red[w * 3 + 1] = s_qq; red[w * 3 + 2] = s_x; }
  __syncthreads();
  if (tid == 0) {
    float a = 0.f, b2 = 0.f, c = 0.f;
    for (int i = 0; i < 8; i++) { a += red[i * 3]; b2 += red[i * 3 + 1]; c += red[i * 3 + 2]; }
    mmd[(long)chunk_start * 5 + bid] = a * (1.f / 15500.f) + b2 * (1.f / 15500.f) - c * (1.f / 15625.f);
  }
}

// =====================================================================
// Kernel D: log-softmax + NLL mean
// =====================================================================
__global__ __launch_bounds__(256) void loss_kernel(const float* __restrict__ mmd,
                                                   const int* __restrict__ qy,
                                                   float* __restrict__ out) {
  __shared__ float red[256];
  int tid = threadIdx.x;
  float val = 0.f;
  if (tid < 150) {
    float l[5];
    float mx = -1e30f;
#pragma unroll
    for (int w = 0; w < 5; w++) {
      l[w] = -mmd[tid * 5 + w] * (1.0f / 12.5f);
      mx = fmaxf(mx, l[w]);
    }
    float sum = 0.f;
#pragma unroll
    for (int w = 0; w < 5; w++) sum += __expf(l[w] - mx);
    float lse = mx + logf(sum);
    int y = qy[tid];
    val = -(l[y] - lse);
  }
  red[tid] = val;
  __syncthreads();
  for (int s = 128; s > 0; s >>= 1) {
    if (tid < s) red[tid] += red[tid + s];
    __syncthreads();
  }
  if (tid == 0) out[0] = red[0] * (1.0f / 150.0f);
}

// =====================================================================
extern "C" void kernel_launch(void* const* d_in, const int* in_sizes, int n_in,
                              void* d_out, int out_size, void* d_ws, size_t ws_size,
                              hipStream_t stream) {
  (void)in_sizes; (void)n_in; (void)out_size;
  const float* sup = (const float*)d_in[0];
  const float* qry = (const float*)d_in[2];
  const int* qy = (const int*)d_in[3];
  const float* Wq = (const float*)d_in[4];
  const float* Wk = (const float*)d_in[5];
  const float* Wv = (const float*)d_in[6];
  float* ws = (float*)d_ws;
  unsigned short* XTB = (unsigned short*)(ws + XTB_OFF);
  unsigned short* WB = (unsigned short*)(ws + WB_OFF);
  unsigned short* projB = (unsigned short*)(ws + PROJB_OFF);
  unsigned short* VT = (unsigned short*)(ws + VT_OFF);
  float* mmd = ws + MMD_OFF;
  unsigned short* feat = (unsigned short*)(ws + FEAT_OFF);
  float* out = (float*)d_out;

  long wsf = (long)(ws_size / 4);
  long avail_us = (wsf - FEAT_OFF) * 2;
  long chunkL = avail_us / FEAT_PER_PAIR_US;
  int chunk = (chunkL > 150) ? 150 : (chunkL < 1 ? 1 : (int)chunkL);

  hipLaunchKernelGGL(t_kernel, dim3(200), dim3(256), 0, stream, sup, qry, XTB);
  hipLaunchKernelGGL(w_kernel, dim3(600), dim3(256), 0, stream, Wq, Wk, Wv, WB);
  hipLaunchKernelGGL(proj_kernel, dim3(40, 5, 3), dim3(512), 0, stream, WB, XTB, projB, VT);
  for (int c0 = 0; c0 < 150; c0 += chunk) {
    int cp = (150 - c0 < chunk) ? (150 - c0) : chunk;
    hipLaunchKernelGGL(attn_kernel, dim3(cp * 50), dim3(256), 0, stream, projB, VT, XTB, feat, c0);
    hipLaunchKernelGGL(gram_kernel, dim3(cp * 5), dim3(512), 0, stream, feat, mmd, c0);
  }
  hipLaunchKernelGGL(loss_kernel, dim3(1), dim3(256), 0, stream, mmd, qy, out);
}

// Round 10
// 266.411 us; speedup vs baseline: 1.4362x; 1.4330x over previous
//
#include <hip/hip_runtime.h>
#include <math.h>

// ---------------- problem constants ----------------
#define PP    25
#define CCH   640
#define NCOL  5000
#define SCALE_INV 0.17677669529663687f   // 1/sqrt(32)

// ---------------- workspace float offsets (r7 layout) ----------------
#define XTB_OFF   0L         // bf16 [5000][640]  (shortcuts + proj B operand)
#define WB_OFF    1600000L   // bf16 [3][640][640]
#define PROJB_OFF 2214400L   // bf16 [3][5000][640], stored [col][o]
#define MMD_OFF   7014400L   // [750]
#define FEAT_OFF  7015168L   // bf16, head-blocked [way][20][250][32]
#define FEAT_PER_WAY_US 160000L
#define FEAT_PER_PAIR_US 800000L

typedef __attribute__((ext_vector_type(8)))  short          s16x8;
typedef __attribute__((ext_vector_type(8)))  unsigned short u16x8;
typedef __attribute__((ext_vector_type(4)))  unsigned short u16x4;
typedef __attribute__((ext_vector_type(16))) float          f32x16;

__device__ inline unsigned short f2bf(float x) {
  unsigned u = __float_as_uint(x);
  unsigned r = u + 0x7fff + ((u >> 16) & 1);   // RNE
  return (unsigned short)(r >> 16);
}
__device__ inline float bf2f(unsigned short b) {
  return __uint_as_float(((unsigned)b) << 16);
}
__device__ inline unsigned cvtpk(float lo, float hi) {
  unsigned r;
  asm("v_cvt_pk_bf16_f32 %0, %1, %2" : "=v"(r) : "v"(lo), "v"(hi));
  return r;
}

// =====================================================================
// Kernel T: build XTB bf16 [col][c]
// =====================================================================
__global__ __launch_bounds__(256) void t_kernel(const float* __restrict__ sup,
                                                const float* __restrict__ qry,
                                                unsigned short* __restrict__ XTB) {
  __shared__ float lds[16000];
  int item = blockIdx.x;
  const float* src = (item < 50) ? (sup + item * 16000) : (qry + (item - 50) * 16000);
  int tid = threadIdx.x;
  for (int e = tid * 4; e < 16000; e += 1024)
    *(float4*)&lds[e] = *(const float4*)&src[e];
  __syncthreads();
  int ibase = item * PP;
  for (int e = tid * 4; e < 16000; e += 1024) {
    int p = e / CCH, c = e - p * CCH;
    u16x4 b;
    b.x = f2bf(lds[(c + 0) * PP + p]);
    b.y = f2bf(lds[(c + 1) * PP + p]);
    b.z = f2bf(lds[(c + 2) * PP + p]);
    b.w = f2bf(lds[(c + 3) * PP + p]);
    *(u16x4*)&XTB[(long)(ibase + p) * CCH + c] = b;
  }
}

// =====================================================================
// Kernel W: Wq/Wk/Wv fp32 -> bf16
// =====================================================================
__global__ __launch_bounds__(256) void w_kernel(const float* __restrict__ Wq,
                                                const float* __restrict__ Wk,
                                                const float* __restrict__ Wv,
                                                unsigned short* __restrict__ WB) {
  long base = ((long)blockIdx.x * 256 + threadIdx.x) * 8;
  int m = (int)(base / 409600L);
  long off = base - (long)m * 409600L;
  const float* W = (m == 0) ? Wq : ((m == 1) ? Wk : Wv);
  float4 a = *(const float4*)&W[off];
  float4 c = *(const float4*)&W[off + 4];
  u16x8 v;
  v[0] = f2bf(a.x); v[1] = f2bf(a.y); v[2] = f2bf(a.z); v[3] = f2bf(a.w);
  v[4] = f2bf(c.x); v[5] = f2bf(c.y); v[6] = f2bf(c.z); v[7] = f2bf(c.w);
  *(u16x8*)&WB[base] = v;
}

// =====================================================================
// Kernel A: MFMA bf16 projections -> bf16 projB [m][col][o]  (r7 form)
// =====================================================================
__global__ __launch_bounds__(512) void proj_kernel(const unsigned short* __restrict__ WB,
                                                   const unsigned short* __restrict__ XTB,
                                                   unsigned short* __restrict__ proj) {
  __shared__ __align__(16) unsigned short At[128 * 64];
  __shared__ __align__(16) unsigned short Bt[128 * 64];
  int m = blockIdx.z;
  int ctile = blockIdx.x * 128, otile = blockIdx.y * 128;
  const unsigned short* Wsrc = WB + (long)m * 409600L;
  unsigned short* out = proj + (long)m * NCOL * CCH;
  int tid = threadIdx.x;
  int w = tid >> 6, lane = tid & 63;
  int wr = w >> 2, wc = w & 3;
  int lr = lane & 31, ksel = lane >> 5;
  int sr = tid >> 2, sg = (tid & 3) * 2;

  f32x16 acc[2];
#pragma unroll
  for (int a = 0; a < 2; a++)
#pragma unroll
    for (int e = 0; e < 16; e++) acc[a][e] = 0.f;

  int bcol = ctile + sr;
  const unsigned short* asrc = Wsrc + (long)(otile + sr) * CCH + sg * 8;
  const unsigned short* bsrc = XTB + (long)bcol * CCH + sg * 8;

  u16x8 pa[2], pb[2];
#pragma unroll
  for (int gi = 0; gi < 2; gi++) {
    pa[gi] = *(const u16x8*)&asrc[gi * 8];
    if (bcol < NCOL) pb[gi] = *(const u16x8*)&bsrc[gi * 8];
    else { u16x8 z; for (int e = 0; e < 8; e++) z[e] = 0; pb[gi] = z; }
  }

  for (int kc = 0; kc < 10; kc++) {
    __syncthreads();
#pragma unroll
    for (int gi = 0; gi < 2; gi++) {
      int g = sg + gi;
      *(u16x8*)&At[sr * 64 + ((g ^ (sr & 7)) << 3)] = pa[gi];
      *(u16x8*)&Bt[sr * 64 + ((g ^ (sr & 7)) << 3)] = pb[gi];
    }
    if (kc < 9) {
      const unsigned short* an = asrc + (kc + 1) * 64;
      const unsigned short* bn = bsrc + (kc + 1) * 64;
#pragma unroll
      for (int gi = 0; gi < 2; gi++) {
        pa[gi] = *(const u16x8*)&an[gi * 8];
        if (bcol < NCOL) pb[gi] = *(const u16x8*)&bn[gi * 8];
      }
    }
    __syncthreads();
#pragma unroll
    for (int ks = 0; ks < 4; ks++) {
      int gk = ks * 2 + ksel;
      s16x8 bf1;
      {
        int R = wc * 32 + lr;
        bf1 = *(const s16x8*)&Bt[R * 64 + ((gk ^ (R & 7)) << 3)];
      }
#pragma unroll
      for (int a = 0; a < 2; a++) {
        int R = (wr + 2 * a) * 32 + lr;
        s16x8 af = *(const s16x8*)&At[R * 64 + ((gk ^ (R & 7)) << 3)];
        acc[a] = __builtin_amdgcn_mfma_f32_32x32x16_bf16(af, bf1, acc[a], 0, 0, 0);
      }
    }
  }

  int col = ctile + wc * 32 + lr;
  if (col < NCOL) {
#pragma unroll
    for (int a = 0; a < 2; a++) {
      int obase = otile + (wr + 2 * a) * 32 + 4 * ksel;
#pragma unroll
      for (int g2 = 0; g2 < 4; g2++) {
        u16x4 v;
        v.x = f2bf(acc[a][g2 * 4 + 0]);
        v.y = f2bf(acc[a][g2 * 4 + 1]);
        v.z = f2bf(acc[a][g2 * 4 + 2]);
        v.w = f2bf(acc[a][g2 * 4 + 3]);
        *(u16x4*)&out[(long)col * CCH + obase + g2 * 8] = v;
      }
    }
  }
}

// =====================================================================
// Kernel B: MFMA attention (r7 structure + VALU cuts).
// One wave per (pair,way,side,head), no LDS. V from projB (r7 pattern).
// =====================================================================
__global__ __launch_bounds__(256) void attn_kernel(const unsigned short* __restrict__ proj,
                                                   const unsigned short* __restrict__ XTB,
                                                   unsigned short* __restrict__ feat,
                                                   int chunk_start) {
  int tid = threadIdx.x, wid = tid >> 6, lane = tid & 63;
  int lr = lane & 31, hf = lane >> 5;
  int rclamp = lr > 24 ? 24 : lr;
  int bid = blockIdx.x;
  int pw = bid / 10, grp = bid - pw * 10;
  int unit = grp * 4 + wid;
  int side = unit >= 20 ? 1 : 0;
  int head = unit - side * 20;
  int lpi = pw / 5, way = pw - lpi * 5;
  int pair = chunk_start + lpi;
  int b = pair / 75;
  int qcol = (50 + pair) * PP;
  int sitem0 = b * 25 + way * 5;
  int ho = head * 32;
  const unsigned short* Qp = proj;
  const unsigned short* Kp = proj + (long)NCOL * CCH;
  const unsigned short* Vp = proj + 2L * NCOL * CCH;
  unsigned short* fb = feat + (long)pw * FEAT_PER_WAY_US + head * 250 * 32;

  // row-fragment: one 16B load
  auto ldfrag = [&](const unsigned short* src, int col0, int ks) -> s16x8 {
    return *(const s16x8*)&src[(long)(col0 + rclamp) * CCH + ho + ks * 16 + hf * 8];
  };
  // V-fragment: base + compile-time j*CCH offsets; NO clamp — slots m>=25
  // are multiplied by P=0 downstream, and worst-case addresses stay inside d_ws.
  auto ldvfrag = [&](int col0, int ks) -> s16x8 {
    const unsigned short* base = Vp + (long)(col0 + ks * 16 + hf * 8) * CCH + ho + lr;
    s16x8 f;
#pragma unroll
    for (int j = 0; j < 8; j++) f[j] = (short)base[(long)j * CCH];
    return f;
  };

  s16x8 fA0, fA1, fB0, fB1, fV0, fV1;
  float scv[16];
  if (side == 0) {               // sbq: Q = query item fixed
    fB0 = ldfrag(Qp, qcol, 0); fB1 = ldfrag(Qp, qcol, 1);
  } else {                       // qbs: K/V = query item fixed; shortcut fixed too
    fA0 = ldfrag(Kp, qcol, 0); fA1 = ldfrag(Kp, qcol, 1);
    fV0 = ldvfrag(qcol, 0);    fV1 = ldvfrag(qcol, 1);
#pragma unroll
    for (int rg = 0; rg < 16; rg++) {
      int q = (rg & 3) + 8 * (rg >> 2) + 4 * hf;
      int qc = q > 24 ? 24 : q;
      scv[rg] = bf2f(XTB[(long)(qcol + qc) * CCH + ho + lr]);
    }
  }

  for (int shot = 0; shot < 5; shot++) {
    int scol = (sitem0 + shot) * PP;
    s16x8 A0, A1, B0, B1, V0, V1;
    if (side == 0) {
      A0 = ldfrag(Kp, scol, 0); A1 = ldfrag(Kp, scol, 1);
      B0 = fB0; B1 = fB1;
      V0 = ldvfrag(scol, 0);    V1 = ldvfrag(scol, 1);
    } else {
      A0 = fA0; A1 = fA1;
      B0 = ldfrag(Qp, scol, 0); B1 = ldfrag(Qp, scol, 1);
      V0 = fV0; V1 = fV1;
    }
    // S^T = K·Q^T : D[m][q], q = lr
    f32x16 s;
#pragma unroll
    for (int e = 0; e < 16; e++) s[e] = 0.f;
    s = __builtin_amdgcn_mfma_f32_32x32x16_bf16(A0, B0, s, 0, 0, 0);
    s = __builtin_amdgcn_mfma_f32_32x32x16_bf16(A1, B1, s, 0, 0, 0);
    // softmax over m for this lane's q
    float pv[16];
    float mx = -1e30f;
#pragma unroll
    for (int rg = 0; rg < 16; rg++) {
      int mm = (rg & 3) + 8 * (rg >> 2) + 4 * hf;
      float v = (mm < 25) ? s[rg] : -1e30f;
      pv[rg] = v;
      mx = fmaxf(mx, v);
    }
    mx = fmaxf(mx, __shfl_xor(mx, 32));
    float sum = 0.f;
#pragma unroll
    for (int rg = 0; rg < 16; rg++) {
      float e = __expf((pv[rg] - mx) * SCALE_INV);
      pv[rg] = e;
      sum += e;
    }
    sum += __shfl_xor(sum, 32);
    float rinv = 1.f / sum;
#pragma unroll
    for (int rg = 0; rg < 16; rg++) pv[rg] *= rinv;
    // P A-frags (half-swap) via cvt_pk
    union { unsigned u[4]; s16x8 v; } P0u, P1u;
    {
      float ex[8], fr[8];
#pragma unroll
      for (int r = 0; r < 8; r++) ex[r] = __shfl_xor(pv[r], 32);
#pragma unroll
      for (int j = 0; j < 4; j++) {
        fr[j]     = hf ? ex[4 + j] : pv[j];
        fr[4 + j] = hf ? pv[4 + j] : ex[j];
      }
#pragma unroll
      for (int j = 0; j < 4; j++) P0u.u[j] = cvtpk(fr[2 * j], fr[2 * j + 1]);
#pragma unroll
      for (int r = 0; r < 8; r++) ex[r] = __shfl_xor(pv[8 + r], 32);
#pragma unroll
      for (int j = 0; j < 4; j++) {
        fr[j]     = hf ? ex[4 + j] : pv[8 + j];
        fr[4 + j] = hf ? pv[12 + j] : ex[j];
      }
#pragma unroll
      for (int j = 0; j < 4; j++) P1u.u[j] = cvtpk(fr[2 * j], fr[2 * j + 1]);
    }
    // O = P·V
    f32x16 o;
#pragma unroll
    for (int e = 0; e < 16; e++) o[e] = 0.f;
    o = __builtin_amdgcn_mfma_f32_32x32x16_bf16(P0u.v, V0, o, 0, 0, 0);
    o = __builtin_amdgcn_mfma_f32_32x32x16_bf16(P1u.v, V1, o, 0, 0, 0);
    // + shortcut, paired cvt_pk, bf16 store (head-blocked)
    unsigned short* frow = fb + (long)((side ? 125 : 0) + shot * 25) * 32;
    const unsigned short* scb = XTB + (long)(scol + 4 * hf) * CCH + ho + lr;
#pragma unroll
    for (int i = 0; i < 8; i++) {
      int rg0 = 2 * i, rg1 = rg0 + 1;
      int qoff = (rg0 & 3) + 8 * (rg0 >> 2);     // compile-time
      int q0 = qoff + 4 * hf, q1 = q0 + 1;
      float sc0, sc1;
      if (side) { sc0 = scv[rg0]; sc1 = scv[rg1]; }
      else {
        sc0 = bf2f(scb[(long)qoff * CCH]);
        sc1 = bf2f(scb[(long)(qoff + 1) * CCH]);
      }
      unsigned u = cvtpk(o[rg0] + sc0, o[rg1] + sc1);
      if (q0 < 25) frow[q0 * 32 + lr] = (unsigned short)u;
      if (q1 < 25) frow[q1 * 32 + lr] = (unsigned short)(u >> 16);
    }
  }
}

// =====================================================================
// Kernel C: MFMA bf16 Gram (rows 0..249 features, row 250 = ones)
// =====================================================================
__device__ inline void gram_load(u16x8* pf, const unsigned short* __restrict__ fb,
                                 int sr, int half, int kc) {
#pragma unroll
  for (int gi = 0; gi < 4; gi++) {
    u16x8 v;
    if (sr < 250) {
      v = *(const u16x8*)&fb[(long)((2 * kc + half) * 250 + sr) * 32 + gi * 8];
    } else if (sr == 250) {
#pragma unroll
      for (int e = 0; e < 8; e++) v[e] = 0x3F80;
    } else {
#pragma unroll
      for (int e = 0; e < 8; e++) v[e] = 0;
    }
    pf[gi] = v;
  }
}

__global__ __launch_bounds__(512) void gram_kernel(const unsigned short* __restrict__ feat,
                                                   float* __restrict__ mmd,
                                                   int chunk_start) {
  __shared__ __align__(16) unsigned short tile[16384];
  __shared__ float sums[256], nrmsq[256], meanv[256], nrmv[256];
  __shared__ float red[24];
  int bid = blockIdx.x;
  const unsigned short* fb = feat + (long)bid * FEAT_PER_WAY_US;
  int tid = threadIdx.x;
  int w = tid >> 6, lane = tid & 63;
  int wr = w >> 2, wc = w & 3;
  int lr = lane & 31, ksel = lane >> 5;
  int sr = tid >> 1, half = tid & 1;

  f32x16 acc[4][2];
#pragma unroll
  for (int a = 0; a < 4; a++)
#pragma unroll
    for (int b2 = 0; b2 < 2; b2++)
#pragma unroll
      for (int e = 0; e < 16; e++) acc[a][b2][e] = 0.f;

  u16x8 pf[4];
  gram_load(pf, fb, sr, half, 0);

  for (int kc = 0; kc < 10; kc++) {
    __syncthreads();
#pragma unroll
    for (int gi = 0; gi < 4; gi++) {
      int g = half * 4 + gi;
      *(u16x8*)&tile[sr * 64 + ((g ^ (sr & 7)) << 3)] = pf[gi];
    }
    if (kc < 9) gram_load(pf, fb, sr, half, kc + 1);
    __syncthreads();
#pragma unroll
    for (int ks = 0; ks < 4; ks++) {
      int gk = ks * 2 + ksel;
      s16x8 af[4], bfv[2];
#pragma unroll
      for (int a = 0; a < 4; a++) {
        int R = (wr + 2 * a) * 32 + lr;
        af[a] = *(const s16x8*)&tile[R * 64 + ((gk ^ (R & 7)) << 3)];
      }
#pragma unroll
      for (int b2 = 0; b2 < 2; b2++) {
        int R = (wc + 4 * b2) * 32 + lr;
        bfv[b2] = *(const s16x8*)&tile[R * 64 + ((gk ^ (R & 7)) << 3)];
      }
#pragma unroll
      for (int a = 0; a < 4; a++)
#pragma unroll
        for (int b2 = 0; b2 < 2; b2++)
          acc[a][b2] = __builtin_amdgcn_mfma_f32_32x32x16_bf16(af[a], bfv[b2], acc[a][b2], 0, 0, 0);
    }
  }

#pragma unroll
  for (int a = 0; a < 4; a++) {
    int ti = wr + 2 * a;
#pragma unroll
    for (int b2 = 0; b2 < 2; b2++) {
      int tj = wc + 4 * b2;
      int col = tj * 32 + lr;
      if (col == 250) {
#pragma unroll
        for (int rg = 0; rg < 16; rg++) {
          int row = ti * 32 + (rg & 3) + 8 * (rg >> 2) + 4 * ksel;
          if (row < 250) sums[row] = acc[a][b2][rg];
        }
      }
      if (ti == tj) {
#pragma unroll
        for (int rg = 0; rg < 16; rg++) {
          int row = ti * 32 + (rg & 3) + 8 * (rg >> 2) + 4 * ksel;
          if (row == col && row < 250) nrmsq[row] = acc[a][b2][rg];
        }
      }
    }
  }
  __syncthreads();
  if (tid < 250) {
    float s0 = sums[tid];
    float m = s0 * (1.f / 640.f);
    meanv[tid] = m;
    nrmv[tid] = nrmsq[tid] - s0 * m;
  }
  __syncthreads();

  float s_ss = 0.f, s_qq = 0.f, s_x = 0.f;
#pragma unroll
  for (int a = 0; a < 4; a++) {
    int ti = wr + 2 * a;
#pragma unroll
    for (int b2 = 0; b2 < 2; b2++) {
      int tj = wc + 4 * b2;
      int col = tj * 32 + lr;
#pragma unroll
      for (int rg = 0; rg < 16; rg++) {
        int row = ti * 32 + (rg & 3) + 8 * (rg >> 2) + 4 * ksel;
        if (row < 250 && col < 250) {
          float d2 = nrmv[row] + nrmv[col] - 2.f * acc[a][b2][rg]
                   + 1280.f * meanv[row] * meanv[col];
          d2 = fmaxf(d2, 0.f);
          float e = __expf(-0.125f * d2);
          float e2 = e * e, e4 = e2 * e2, e8 = e4 * e4, e16 = e8 * e8;
          float kv = e + e2 + e4 + e8 + e16;
          bool rs = row < 125, cs = col < 125;
          if (rs && cs)        { if (row != col) s_ss += kv; }
          else if (!rs && !cs) { if (row != col) s_qq += kv; }
          else                 s_x += kv;
        }
      }
    }
  }
#pragma unroll
  for (int off = 32; off; off >>= 1) {
    s_ss += __shfl_xor(s_ss, off);
    s_qq += __shfl_xor(s_qq, off);
    s_x  += __shfl_xor(s_x, off);
  }
  if (lane == 0) { red[w * 3] = s_ss; red[w * 3 + 1] = s_qq; red[w * 3 + 2] = s_x; }
  __syncthreads();
  if (tid == 0) {
    float a = 0.f, b2 = 0.f, c = 0.f;
    for (int i = 0; i < 8; i++) { a += red[i * 3]; b2 += red[i * 3 + 1]; c += red[i * 3 + 2]; }
    mmd[(long)chunk_start * 5 + bid] = a * (1.f / 15500.f) + b2 * (1.f / 15500.f) - c * (1.f / 15625.f);
  }
}

// =====================================================================
// Kernel D: log-softmax + NLL mean
// =====================================================================
__global__ __launch_bounds__(256) void loss_kernel(const float* __restrict__ mmd,
                                                   const int* __restrict__ qy,
                                                   float* __restrict__ out) {
  __shared__ float red[256];
  int tid = threadIdx.x;
  float val = 0.f;
  if (tid < 150) {
    float l[5];
    float mx = -1e30f;
#pragma unroll
    for (int w = 0; w < 5; w++) {
      l[w] = -mmd[tid * 5 + w] * (1.0f / 12.5f);
      mx = fmaxf(mx, l[w]);
    }
    float sum = 0.f;
#pragma unroll
    for (int w = 0; w < 5; w++) sum += __expf(l[w] - mx);
    float lse = mx + logf(sum);
    int y = qy[tid];
    val = -(l[y] - lse);
  }
  red[tid] = val;
  __syncthreads();
  for (int s = 128; s > 0; s >>= 1) {
    if (tid < s) red[tid] += red[tid + s];
    __syncthreads();
  }
  if (tid == 0) out[0] = red[0] * (1.0f / 150.0f);
}

// =====================================================================
extern "C" void kernel_launch(void* const* d_in, const int* in_sizes, int n_in,
                              void* d_out, int out_size, void* d_ws, size_t ws_size,
                              hipStream_t stream) {
  (void)in_sizes; (void)n_in; (void)out_size;
  const float* sup = (const float*)d_in[0];
  const float* qry = (const float*)d_in[2];
  const int* qy = (const int*)d_in[3];
  const float* Wq = (const float*)d_in[4];
  const float* Wk = (const float*)d_in[5];
  const float* Wv = (const float*)d_in[6];
  float* ws = (float*)d_ws;
  unsigned short* XTB = (unsigned short*)(ws + XTB_OFF);
  unsigned short* WB = (unsigned short*)(ws + WB_OFF);
  unsigned short* projB = (unsigned short*)(ws + PROJB_OFF);
  float* mmd = ws + MMD_OFF;
  unsigned short* feat = (unsigned short*)(ws + FEAT_OFF);
  float* out = (float*)d_out;

  long wsf = (long)(ws_size / 4);
  long avail_us = (wsf - FEAT_OFF) * 2;
  long chunkL = avail_us / FEAT_PER_PAIR_US;
  int chunk = (chunkL > 150) ? 150 : (chunkL < 1 ? 1 : (int)chunkL);

  hipLaunchKernelGGL(t_kernel, dim3(200), dim3(256), 0, stream, sup, qry, XTB);
  hipLaunchKernelGGL(w_kernel, dim3(600), dim3(256), 0, stream, Wq, Wk, Wv, WB);
  hipLaunchKernelGGL(proj_kernel, dim3(40, 5, 3), dim3(512), 0, stream, WB, XTB, projB);
  for (int c0 = 0; c0 < 150; c0 += chunk) {
    int cp = (150 - c0 < chunk) ? (150 - c0) : chunk;
    hipLaunchKernelGGL(attn_kernel, dim3(cp * 50), dim3(256), 0, stream, projB, XTB, feat, c0);
    hipLaunchKernelGGL(gram_kernel, dim3(cp * 5), dim3(512), 0, stream, feat, mmd, c0);
  }
  hipLaunchKernelGGL(loss_kernel, dim3(1), dim3(256), 0, stream, mmd, qy, out);
}

// Round 11
// 263.135 us; speedup vs baseline: 1.4541x; 1.0125x over previous
//
#include <hip/hip_runtime.h>
#include <math.h>

// ---------------- problem constants ----------------
#define PP    25
#define CCH   640
#define NCOL  5000
#define SCALE_INV 0.17677669529663687f   // 1/sqrt(32)

// ---------------- workspace float offsets ----------------
#define XTB_OFF   0L         // bf16 [5000][640]
#define WB_OFF    1600000L   // bf16 [3][640][640]
#define PROJB_OFF 2214400L   // bf16 [3][5000][640], stored [col][o]
#define MMD_OFF   7014400L   // [750]
#define ONES_OFF  7015168L   // bf16 [6][64]: row250=1.0, 251-255=0
#define FEAT_OFF  7015360L   // bf16, head-blocked [way][20][250][32]
#define FEAT_PER_WAY_US 160000L
#define FEAT_PER_PAIR_US 800000L

typedef __attribute__((ext_vector_type(8)))  short          s16x8;
typedef __attribute__((ext_vector_type(8)))  unsigned short u16x8;
typedef __attribute__((ext_vector_type(4)))  unsigned short u16x4;
typedef __attribute__((ext_vector_type(16))) float          f32x16;

typedef __attribute__((address_space(1))) const unsigned int glb_u32;
typedef __attribute__((address_space(3))) unsigned int       lds_u32;

__device__ inline unsigned short f2bf(float x) {
  unsigned u = __float_as_uint(x);
  unsigned r = u + 0x7fff + ((u >> 16) & 1);   // RNE
  return (unsigned short)(r >> 16);
}
__device__ inline float bf2f(unsigned short b) {
  return __uint_as_float(((unsigned)b) << 16);
}
__device__ inline unsigned cvtpk(float lo, float hi) {
  unsigned r;
  asm("v_cvt_pk_bf16_f32 %0, %1, %2" : "=v"(r) : "v"(lo), "v"(hi));
  return r;
}

// =====================================================================
// Kernel T: build XTB bf16 [col][c]
// =====================================================================
__global__ __launch_bounds__(256) void t_kernel(const float* __restrict__ sup,
                                                const float* __restrict__ qry,
                                                unsigned short* __restrict__ XTB) {
  __shared__ float lds[16000];
  int item = blockIdx.x;
  const float* src = (item < 50) ? (sup + item * 16000) : (qry + (item - 50) * 16000);
  int tid = threadIdx.x;
  for (int e = tid * 4; e < 16000; e += 1024)
    *(float4*)&lds[e] = *(const float4*)&src[e];
  __syncthreads();
  int ibase = item * PP;
  for (int e = tid * 4; e < 16000; e += 1024) {
    int p = e / CCH, c = e - p * CCH;
    u16x4 b;
    b.x = f2bf(lds[(c + 0) * PP + p]);
    b.y = f2bf(lds[(c + 1) * PP + p]);
    b.z = f2bf(lds[(c + 2) * PP + p]);
    b.w = f2bf(lds[(c + 3) * PP + p]);
    *(u16x4*)&XTB[(long)(ibase + p) * CCH + c] = b;
  }
}

// =====================================================================
// Kernel W: Wq/Wk/Wv fp32 -> bf16; block 0 also inits the ones region
// =====================================================================
__global__ __launch_bounds__(256) void w_kernel(const float* __restrict__ Wq,
                                                const float* __restrict__ Wk,
                                                const float* __restrict__ Wv,
                                                unsigned short* __restrict__ WB,
                                                unsigned short* __restrict__ ones) {
  if (blockIdx.x == 0 && threadIdx.x < 384)
    ones[threadIdx.x] = (threadIdx.x < 64) ? (unsigned short)0x3F80 : (unsigned short)0;
  long base = ((long)blockIdx.x * 256 + threadIdx.x) * 8;
  int m = (int)(base / 409600L);
  long off = base - (long)m * 409600L;
  const float* W = (m == 0) ? Wq : ((m == 1) ? Wk : Wv);
  float4 a = *(const float4*)&W[off];
  float4 c = *(const float4*)&W[off + 4];
  u16x8 v;
  v[0] = f2bf(a.x); v[1] = f2bf(a.y); v[2] = f2bf(a.z); v[3] = f2bf(a.w);
  v[4] = f2bf(c.x); v[5] = f2bf(c.y); v[6] = f2bf(c.z); v[7] = f2bf(c.w);
  *(u16x8*)&WB[base] = v;
}

// =====================================================================
// Kernel A: MFMA bf16 projections -> bf16 projB [m][col][o]
// =====================================================================
__global__ __launch_bounds__(512) void proj_kernel(const unsigned short* __restrict__ WB,
                                                   const unsigned short* __restrict__ XTB,
                                                   unsigned short* __restrict__ proj) {
  __shared__ __align__(16) unsigned short At[128 * 64];
  __shared__ __align__(16) unsigned short Bt[128 * 64];
  int m = blockIdx.z;
  int ctile = blockIdx.x * 128, otile = blockIdx.y * 128;
  const unsigned short* Wsrc = WB + (long)m * 409600L;
  unsigned short* out = proj + (long)m * NCOL * CCH;
  int tid = threadIdx.x;
  int w = tid >> 6, lane = tid & 63;
  int wr = w >> 2, wc = w & 3;
  int lr = lane & 31, ksel = lane >> 5;
  int sr = tid >> 2, sg = (tid & 3) * 2;

  f32x16 acc[2];
#pragma unroll
  for (int a = 0; a < 2; a++)
#pragma unroll
    for (int e = 0; e < 16; e++) acc[a][e] = 0.f;

  int bcol = ctile + sr;
  const unsigned short* asrc = Wsrc + (long)(otile + sr) * CCH + sg * 8;
  const unsigned short* bsrc = XTB + (long)bcol * CCH + sg * 8;

  u16x8 pa[2], pb[2];
#pragma unroll
  for (int gi = 0; gi < 2; gi++) {
    pa[gi] = *(const u16x8*)&asrc[gi * 8];
    if (bcol < NCOL) pb[gi] = *(const u16x8*)&bsrc[gi * 8];
    else { u16x8 z; for (int e = 0; e < 8; e++) z[e] = 0; pb[gi] = z; }
  }

  for (int kc = 0; kc < 10; kc++) {
    __syncthreads();
#pragma unroll
    for (int gi = 0; gi < 2; gi++) {
      int g = sg + gi;
      *(u16x8*)&At[sr * 64 + ((g ^ (sr & 7)) << 3)] = pa[gi];
      *(u16x8*)&Bt[sr * 64 + ((g ^ (sr & 7)) << 3)] = pb[gi];
    }
    if (kc < 9) {
      const unsigned short* an = asrc + (kc + 1) * 64;
      const unsigned short* bn = bsrc + (kc + 1) * 64;
#pragma unroll
      for (int gi = 0; gi < 2; gi++) {
        pa[gi] = *(const u16x8*)&an[gi * 8];
        if (bcol < NCOL) pb[gi] = *(const u16x8*)&bn[gi * 8];
      }
    }
    __syncthreads();
#pragma unroll
    for (int ks = 0; ks < 4; ks++) {
      int gk = ks * 2 + ksel;
      s16x8 bf1;
      {
        int R = wc * 32 + lr;
        bf1 = *(const s16x8*)&Bt[R * 64 + ((gk ^ (R & 7)) << 3)];
      }
#pragma unroll
      for (int a = 0; a < 2; a++) {
        int R = (wr + 2 * a) * 32 + lr;
        s16x8 af = *(const s16x8*)&At[R * 64 + ((gk ^ (R & 7)) << 3)];
        acc[a] = __builtin_amdgcn_mfma_f32_32x32x16_bf16(af, bf1, acc[a], 0, 0, 0);
      }
    }
  }

  int col = ctile + wc * 32 + lr;
  if (col < NCOL) {
#pragma unroll
    for (int a = 0; a < 2; a++) {
      int obase = otile + (wr + 2 * a) * 32 + 4 * ksel;
#pragma unroll
      for (int g2 = 0; g2 < 4; g2++) {
        u16x4 v;
        v.x = f2bf(acc[a][g2 * 4 + 0]);
        v.y = f2bf(acc[a][g2 * 4 + 1]);
        v.z = f2bf(acc[a][g2 * 4 + 2]);
        v.w = f2bf(acc[a][g2 * 4 + 3]);
        *(u16x4*)&out[(long)col * CCH + obase + g2 * 8] = v;
      }
    }
  }
}

// =====================================================================
// Kernel B: MFMA attention (r10 structure, unchanged)
// =====================================================================
__global__ __launch_bounds__(256) void attn_kernel(const unsigned short* __restrict__ proj,
                                                   const unsigned short* __restrict__ XTB,
                                                   unsigned short* __restrict__ feat,
                                                   int chunk_start) {
  int tid = threadIdx.x, wid = tid >> 6, lane = tid & 63;
  int lr = lane & 31, hf = lane >> 5;
  int rclamp = lr > 24 ? 24 : lr;
  int bid = blockIdx.x;
  int pw = bid / 10, grp = bid - pw * 10;
  int unit = grp * 4 + wid;
  int side = unit >= 20 ? 1 : 0;
  int head = unit - side * 20;
  int lpi = pw / 5, way = pw - lpi * 5;
  int pair = chunk_start + lpi;
  int b = pair / 75;
  int qcol = (50 + pair) * PP;
  int sitem0 = b * 25 + way * 5;
  int ho = head * 32;
  const unsigned short* Qp = proj;
  const unsigned short* Kp = proj + (long)NCOL * CCH;
  const unsigned short* Vp = proj + 2L * NCOL * CCH;
  unsigned short* fb = feat + (long)pw * FEAT_PER_WAY_US + head * 250 * 32;

  auto ldfrag = [&](const unsigned short* src, int col0, int ks) -> s16x8 {
    return *(const s16x8*)&src[(long)(col0 + rclamp) * CCH + ho + ks * 16 + hf * 8];
  };
  auto ldvfrag = [&](int col0, int ks) -> s16x8 {
    const unsigned short* base = Vp + (long)(col0 + ks * 16 + hf * 8) * CCH + ho + lr;
    s16x8 f;
#pragma unroll
    for (int j = 0; j < 8; j++) f[j] = (short)base[(long)j * CCH];
    return f;
  };

  s16x8 fA0, fA1, fB0, fB1, fV0, fV1;
  float scv[16];
  if (side == 0) {
    fB0 = ldfrag(Qp, qcol, 0); fB1 = ldfrag(Qp, qcol, 1);
  } else {
    fA0 = ldfrag(Kp, qcol, 0); fA1 = ldfrag(Kp, qcol, 1);
    fV0 = ldvfrag(qcol, 0);    fV1 = ldvfrag(qcol, 1);
#pragma unroll
    for (int rg = 0; rg < 16; rg++) {
      int q = (rg & 3) + 8 * (rg >> 2) + 4 * hf;
      int qc = q > 24 ? 24 : q;
      scv[rg] = bf2f(XTB[(long)(qcol + qc) * CCH + ho + lr]);
    }
  }

  for (int shot = 0; shot < 5; shot++) {
    int scol = (sitem0 + shot) * PP;
    s16x8 A0, A1, B0, B1, V0, V1;
    if (side == 0) {
      A0 = ldfrag(Kp, scol, 0); A1 = ldfrag(Kp, scol, 1);
      B0 = fB0; B1 = fB1;
      V0 = ldvfrag(scol, 0);    V1 = ldvfrag(scol, 1);
    } else {
      A0 = fA0; A1 = fA1;
      B0 = ldfrag(Qp, scol, 0); B1 = ldfrag(Qp, scol, 1);
      V0 = fV0; V1 = fV1;
    }
    f32x16 s;
#pragma unroll
    for (int e = 0; e < 16; e++) s[e] = 0.f;
    s = __builtin_amdgcn_mfma_f32_32x32x16_bf16(A0, B0, s, 0, 0, 0);
    s = __builtin_amdgcn_mfma_f32_32x32x16_bf16(A1, B1, s, 0, 0, 0);
    float pv[16];
    float mx = -1e30f;
#pragma unroll
    for (int rg = 0; rg < 16; rg++) {
      int mm = (rg & 3) + 8 * (rg >> 2) + 4 * hf;
      float v = (mm < 25) ? s[rg] : -1e30f;
      pv[rg] = v;
      mx = fmaxf(mx, v);
    }
    mx = fmaxf(mx, __shfl_xor(mx, 32));
    float sum = 0.f;
#pragma unroll
    for (int rg = 0; rg < 16; rg++) {
      float e = __expf((pv[rg] - mx) * SCALE_INV);
      pv[rg] = e;
      sum += e;
    }
    sum += __shfl_xor(sum, 32);
    float rinv = 1.f / sum;
#pragma unroll
    for (int rg = 0; rg < 16; rg++) pv[rg] *= rinv;
    union { unsigned u[4]; s16x8 v; } P0u, P1u;
    {
      float ex[8], fr[8];
#pragma unroll
      for (int r = 0; r < 8; r++) ex[r] = __shfl_xor(pv[r], 32);
#pragma unroll
      for (int j = 0; j < 4; j++) {
        fr[j]     = hf ? ex[4 + j] : pv[j];
        fr[4 + j] = hf ? pv[4 + j] : ex[j];
      }
#pragma unroll
      for (int j = 0; j < 4; j++) P0u.u[j] = cvtpk(fr[2 * j], fr[2 * j + 1]);
#pragma unroll
      for (int r = 0; r < 8; r++) ex[r] = __shfl_xor(pv[8 + r], 32);
#pragma unroll
      for (int j = 0; j < 4; j++) {
        fr[j]     = hf ? ex[4 + j] : pv[8 + j];
        fr[4 + j] = hf ? pv[12 + j] : ex[j];
      }
#pragma unroll
      for (int j = 0; j < 4; j++) P1u.u[j] = cvtpk(fr[2 * j], fr[2 * j + 1]);
    }
    f32x16 o;
#pragma unroll
    for (int e = 0; e < 16; e++) o[e] = 0.f;
    o = __builtin_amdgcn_mfma_f32_32x32x16_bf16(P0u.v, V0, o, 0, 0, 0);
    o = __builtin_amdgcn_mfma_f32_32x32x16_bf16(P1u.v, V1, o, 0, 0, 0);
    unsigned short* frow = fb + (long)((side ? 125 : 0) + shot * 25) * 32;
    const unsigned short* scb = XTB + (long)(scol + 4 * hf) * CCH + ho + lr;
#pragma unroll
    for (int i = 0; i < 8; i++) {
      int rg0 = 2 * i, rg1 = rg0 + 1;
      int qoff = (rg0 & 3) + 8 * (rg0 >> 2);
      int q0 = qoff + 4 * hf, q1 = q0 + 1;
      float sc0, sc1;
      if (side) { sc0 = scv[rg0]; sc1 = scv[rg1]; }
      else {
        sc0 = bf2f(scb[(long)qoff * CCH]);
        sc1 = bf2f(scb[(long)(qoff + 1) * CCH]);
      }
      unsigned u = cvtpk(o[rg0] + sc0, o[rg1] + sc1);
      if (q0 < 25) frow[q0 * 32 + lr] = (unsigned short)u;
      if (q1 < 25) frow[q1 * 32 + lr] = (unsigned short)(u >> 16);
    }
  }
}

// =====================================================================
// Kernel C: MFMA bf16 Gram — global_load_lds staging, double-buffered.
// LDS slot s holds (row=s>>3, gslot=s&7) <- global granule g=gslot^(row&7)
// via pre-swizzled per-lane source (read path identical to r10).
// =====================================================================
__global__ __launch_bounds__(512, 2) void gram_kernel(const unsigned short* __restrict__ feat,
                                                      const unsigned short* __restrict__ ones,
                                                      float* __restrict__ mmd,
                                                      int chunk_start) {
  __shared__ __align__(16) unsigned short tile[2][16384];
  __shared__ float sums[256], nrmsq[256], meanv[256], nrmv[256];
  __shared__ float red[24];
  int bid = blockIdx.x;
  const unsigned short* fb = feat + (long)bid * FEAT_PER_WAY_US;
  int tid = threadIdx.x;
  int w = tid >> 6, lane = tid & 63;
  int wr = w >> 2, wc = w & 3;
  int lr = lane & 31, ksel = lane >> 5;

  // per-lane pre-swizzled staging sources (4 gload_lds per wave per kc)
  const unsigned short* srcp[4];
  long stepv[4];
#pragma unroll
  for (int i = 0; i < 4; i++) {
    int s = (w * 4 + i) * 64 + lane;
    int row = s >> 3, gs = s & 7, g = gs ^ (row & 7);
    if (row < 250) {
      srcp[i] = fb + (long)((g >> 2) * 250 + row) * 32 + (g & 3) * 8;
      stepv[i] = 16000;      // advance 2 heads (64 ch) per kc
    } else {
      srcp[i] = ones + (row - 250) * 64 + g * 8;
      stepv[i] = 0;
    }
  }

  f32x16 acc[4][2];
#pragma unroll
  for (int a = 0; a < 4; a++)
#pragma unroll
    for (int b2 = 0; b2 < 2; b2++)
#pragma unroll
      for (int e = 0; e < 16; e++) acc[a][b2][e] = 0.f;

  // prologue: stage kc=0 into buf 0
#pragma unroll
  for (int i = 0; i < 4; i++)
    __builtin_amdgcn_global_load_lds((glb_u32*)srcp[i],
                                     (lds_u32*)&tile[0][(w * 4 + i) * 512], 16, 0, 0);
  __syncthreads();

  for (int kc = 0; kc < 10; kc++) {
    int cur = kc & 1;
    if (kc < 9) {
#pragma unroll
      for (int i = 0; i < 4; i++)
        __builtin_amdgcn_global_load_lds((glb_u32*)(srcp[i] + (long)(kc + 1) * stepv[i]),
                                         (lds_u32*)&tile[cur ^ 1][(w * 4 + i) * 512], 16, 0, 0);
    }
    const unsigned short* tb = tile[cur];
#pragma unroll
    for (int ks = 0; ks < 4; ks++) {
      int gk = ks * 2 + ksel;
      s16x8 af[4], bfv[2];
#pragma unroll
      for (int a = 0; a < 4; a++) {
        int R = (wr + 2 * a) * 32 + lr;
        af[a] = *(const s16x8*)&tb[R * 64 + ((gk ^ (R & 7)) << 3)];
      }
#pragma unroll
      for (int b2 = 0; b2 < 2; b2++) {
        int R = (wc + 4 * b2) * 32 + lr;
        bfv[b2] = *(const s16x8*)&tb[R * 64 + ((gk ^ (R & 7)) << 3)];
      }
#pragma unroll
      for (int a = 0; a < 4; a++)
#pragma unroll
        for (int b2 = 0; b2 < 2; b2++)
          acc[a][b2] = __builtin_amdgcn_mfma_f32_32x32x16_bf16(af[a], bfv[b2], acc[a][b2], 0, 0, 0);
    }
    __syncthreads();   // drains vmcnt (next buf landed) + lgkmcnt (reads done)
  }

  // ---- harvest row sums (col 250) and squared norms (diagonal) ----
#pragma unroll
  for (int a = 0; a < 4; a++) {
    int ti = wr + 2 * a;
#pragma unroll
    for (int b2 = 0; b2 < 2; b2++) {
      int tj = wc + 4 * b2;
      int col = tj * 32 + lr;
      if (col == 250) {
#pragma unroll
        for (int rg = 0; rg < 16; rg++) {
          int row = ti * 32 + (rg & 3) + 8 * (rg >> 2) + 4 * ksel;
          if (row < 250) sums[row] = acc[a][b2][rg];
        }
      }
      if (ti == tj) {
#pragma unroll
        for (int rg = 0; rg < 16; rg++) {
          int row = ti * 32 + (rg & 3) + 8 * (rg >> 2) + 4 * ksel;
          if (row == col && row < 250) nrmsq[row] = acc[a][b2][rg];
        }
      }
    }
  }
  __syncthreads();
  if (tid < 250) {
    float s0 = sums[tid];
    float m = s0 * (1.f / 640.f);
    meanv[tid] = m;
    nrmv[tid] = nrmsq[tid] - s0 * m;
  }
  __syncthreads();

  float s_ss = 0.f, s_qq = 0.f, s_x = 0.f;
#pragma unroll
  for (int a = 0; a < 4; a++) {
    int ti = wr + 2 * a;
#pragma unroll
    for (int b2 = 0; b2 < 2; b2++) {
      int tj = wc + 4 * b2;
      int col = tj * 32 + lr;
#pragma unroll
      for (int rg = 0; rg < 16; rg++) {
        int row = ti * 32 + (rg & 3) + 8 * (rg >> 2) + 4 * ksel;
        if (row < 250 && col < 250) {
          float d2 = nrmv[row] + nrmv[col] - 2.f * acc[a][b2][rg]
                   + 1280.f * meanv[row] * meanv[col];
          d2 = fmaxf(d2, 0.f);
          float e = __expf(-0.125f * d2);
          float e2 = e * e, e4 = e2 * e2, e8 = e4 * e4, e16 = e8 * e8;
          float kv = e + e2 + e4 + e8 + e16;
          bool rs = row < 125, cs = col < 125;
          if (rs && cs)        { if (row != col) s_ss += kv; }
          else if (!rs && !cs) { if (row != col) s_qq += kv; }
          else                 s_x += kv;
        }
      }
    }
  }
#pragma unroll
  for (int off = 32; off; off >>= 1) {
    s_ss += __shfl_xor(s_ss, off);
    s_qq += __shfl_xor(s_qq, off);
    s_x  += __shfl_xor(s_x, off);
  }
  if (lane == 0) { red[w * 3] = s_ss; red[w * 3 + 1] = s_qq; red[w * 3 + 2] = s_x; }
  __syncthreads();
  if (tid == 0) {
    float a = 0.f, b2 = 0.f, c = 0.f;
    for (int i = 0; i < 8; i++) { a += red[i * 3]; b2 += red[i * 3 + 1]; c += red[i * 3 + 2]; }
    mmd[(long)chunk_start * 5 + bid] = a * (1.f / 15500.f) + b2 * (1.f / 15500.f) - c * (1.f / 15625.f);
  }
}

// =====================================================================
// Kernel D: log-softmax + NLL mean
// =====================================================================
__global__ __launch_bounds__(256) void loss_kernel(const float* __restrict__ mmd,
                                                   const int* __restrict__ qy,
                                                   float* __restrict__ out) {
  __shared__ float red[256];
  int tid = threadIdx.x;
  float val = 0.f;
  if (tid < 150) {
    float l[5];
    float mx = -1e30f;
#pragma unroll
    for (int w = 0; w < 5; w++) {
      l[w] = -mmd[tid * 5 + w] * (1.0f / 12.5f);
      mx = fmaxf(mx, l[w]);
    }
    float sum = 0.f;
#pragma unroll
    for (int w = 0; w < 5; w++) sum += __expf(l[w] - mx);
    float lse = mx + logf(sum);
    int y = qy[tid];
    val = -(l[y] - lse);
  }
  red[tid] = val;
  __syncthreads();
  for (int s = 128; s > 0; s >>= 1) {
    if (tid < s) red[tid] += red[tid + s];
    __syncthreads();
  }
  if (tid == 0) out[0] = red[0] * (1.0f / 150.0f);
}

// =====================================================================
extern "C" void kernel_launch(void* const* d_in, const int* in_sizes, int n_in,
                              void* d_out, int out_size, void* d_ws, size_t ws_size,
                              hipStream_t stream) {
  (void)in_sizes; (void)n_in; (void)out_size;
  const float* sup = (const float*)d_in[0];
  const float* qry = (const float*)d_in[2];
  const int* qy = (const int*)d_in[3];
  const float* Wq = (const float*)d_in[4];
  const float* Wk = (const float*)d_in[5];
  const float* Wv = (const float*)d_in[6];
  float* ws = (float*)d_ws;
  unsigned short* XTB = (unsigned short*)(ws + XTB_OFF);
  unsigned short* WB = (unsigned short*)(ws + WB_OFF);
  unsigned short* projB = (unsigned short*)(ws + PROJB_OFF);
  float* mmd = ws + MMD_OFF;
  unsigned short* ones = (unsigned short*)(ws + ONES_OFF);
  unsigned short* feat = (unsigned short*)(ws + FEAT_OFF);
  float* out = (float*)d_out;

  long wsf = (long)(ws_size / 4);
  long avail_us = (wsf - FEAT_OFF) * 2;
  long chunkL = avail_us / FEAT_PER_PAIR_US;
  int chunk = (chunkL > 150) ? 150 : (chunkL < 1 ? 1 : (int)chunkL);

  hipLaunchKernelGGL(t_kernel, dim3(200), dim3(256), 0, stream, sup, qry, XTB);
  hipLaunchKernelGGL(w_kernel, dim3(600), dim3(256), 0, stream, Wq, Wk, Wv, WB, ones);
  hipLaunchKernelGGL(proj_kernel, dim3(40, 5, 3), dim3(512), 0, stream, WB, XTB, projB);
  for (int c0 = 0; c0 < 150; c0 += chunk) {
    int cp = (150 - c0 < chunk) ? (150 - c0) : chunk;
    hipLaunchKernelGGL(attn_kernel, dim3(cp * 50), dim3(256), 0, stream, projB, XTB, feat, c0);
    hipLaunchKernelGGL(gram_kernel, dim3(cp * 5), dim3(512), 0, stream, feat, ones, mmd, c0);
  }
  hipLaunchKernelGGL(loss_kernel, dim3(1), dim3(256), 0, stream, mmd, qy, out);
}

// Round 12
// 259.954 us; speedup vs baseline: 1.4719x; 1.0122x over previous
//
#include <hip/hip_runtime.h>
#include <math.h>

// ---------------- problem constants ----------------
#define PP    25
#define CCH   640
#define NCOL  5000
#define SCALE_INV 0.17677669529663687f   // 1/sqrt(32)

// ---------------- workspace float offsets ----------------
#define XTB_OFF   0L         // bf16 [5000][640]
#define WB_OFF    1600000L   // bf16 [3][640][640]
#define PROJB_OFF 2214400L   // bf16 [3][5000][640], stored [col][o]
#define MMD_OFF   7014400L   // [750]
#define ONES_OFF  7015168L   // bf16 [6][64]: row250=1.0, 251-255=0
#define FEAT_OFF  7015360L   // bf16, head-blocked [way][20][250][32]
#define FEAT_PER_WAY_US 160000L
#define FEAT_PER_PAIR_US 800000L

typedef __attribute__((ext_vector_type(8)))  short          s16x8;
typedef __attribute__((ext_vector_type(8)))  unsigned short u16x8;
typedef __attribute__((ext_vector_type(4)))  unsigned short u16x4;
typedef __attribute__((ext_vector_type(16))) float          f32x16;

typedef __attribute__((address_space(1))) const unsigned int glb_u32;
typedef __attribute__((address_space(3))) unsigned int       lds_u32;

__device__ inline unsigned short f2bf(float x) {
  unsigned u = __float_as_uint(x);
  unsigned r = u + 0x7fff + ((u >> 16) & 1);   // RNE
  return (unsigned short)(r >> 16);
}
__device__ inline float bf2f(unsigned short b) {
  return __uint_as_float(((unsigned)b) << 16);
}
__device__ inline unsigned cvtpk(float lo, float hi) {
  unsigned r;
  asm("v_cvt_pk_bf16_f32 %0, %1, %2" : "=v"(r) : "v"(lo), "v"(hi));
  return r;
}

// =====================================================================
// Kernel T: build XTB bf16 [col][c]
// =====================================================================
__global__ __launch_bounds__(256) void t_kernel(const float* __restrict__ sup,
                                                const float* __restrict__ qry,
                                                unsigned short* __restrict__ XTB) {
  __shared__ float lds[16000];
  int item = blockIdx.x;
  const float* src = (item < 50) ? (sup + item * 16000) : (qry + (item - 50) * 16000);
  int tid = threadIdx.x;
  for (int e = tid * 4; e < 16000; e += 1024)
    *(float4*)&lds[e] = *(const float4*)&src[e];
  __syncthreads();
  int ibase = item * PP;
  for (int e = tid * 4; e < 16000; e += 1024) {
    int p = e / CCH, c = e - p * CCH;
    u16x4 b;
    b.x = f2bf(lds[(c + 0) * PP + p]);
    b.y = f2bf(lds[(c + 1) * PP + p]);
    b.z = f2bf(lds[(c + 2) * PP + p]);
    b.w = f2bf(lds[(c + 3) * PP + p]);
    *(u16x4*)&XTB[(long)(ibase + p) * CCH + c] = b;
  }
}

// =====================================================================
// Kernel W: Wq/Wk/Wv fp32 -> bf16; block 0 also inits the ones region
// =====================================================================
__global__ __launch_bounds__(256) void w_kernel(const float* __restrict__ Wq,
                                                const float* __restrict__ Wk,
                                                const float* __restrict__ Wv,
                                                unsigned short* __restrict__ WB,
                                                unsigned short* __restrict__ ones) {
  if (blockIdx.x == 0 && threadIdx.x < 384)
    ones[threadIdx.x] = (threadIdx.x < 64) ? (unsigned short)0x3F80 : (unsigned short)0;
  long base = ((long)blockIdx.x * 256 + threadIdx.x) * 8;
  int m = (int)(base / 409600L);
  long off = base - (long)m * 409600L;
  const float* W = (m == 0) ? Wq : ((m == 1) ? Wk : Wv);
  float4 a = *(const float4*)&W[off];
  float4 c = *(const float4*)&W[off + 4];
  u16x8 v;
  v[0] = f2bf(a.x); v[1] = f2bf(a.y); v[2] = f2bf(a.z); v[3] = f2bf(a.w);
  v[4] = f2bf(c.x); v[5] = f2bf(c.y); v[6] = f2bf(c.z); v[7] = f2bf(c.w);
  *(u16x8*)&WB[base] = v;
}

// =====================================================================
// Kernel A: MFMA bf16 projections -> bf16 projB [m][col][o]
// =====================================================================
__global__ __launch_bounds__(512) void proj_kernel(const unsigned short* __restrict__ WB,
                                                   const unsigned short* __restrict__ XTB,
                                                   unsigned short* __restrict__ proj) {
  __shared__ __align__(16) unsigned short At[128 * 64];
  __shared__ __align__(16) unsigned short Bt[128 * 64];
  int m = blockIdx.z;
  int ctile = blockIdx.x * 128, otile = blockIdx.y * 128;
  const unsigned short* Wsrc = WB + (long)m * 409600L;
  unsigned short* out = proj + (long)m * NCOL * CCH;
  int tid = threadIdx.x;
  int w = tid >> 6, lane = tid & 63;
  int wr = w >> 2, wc = w & 3;
  int lr = lane & 31, ksel = lane >> 5;
  int sr = tid >> 2, sg = (tid & 3) * 2;

  f32x16 acc[2];
#pragma unroll
  for (int a = 0; a < 2; a++)
#pragma unroll
    for (int e = 0; e < 16; e++) acc[a][e] = 0.f;

  int bcol = ctile + sr;
  const unsigned short* asrc = Wsrc + (long)(otile + sr) * CCH + sg * 8;
  const unsigned short* bsrc = XTB + (long)bcol * CCH + sg * 8;

  u16x8 pa[2], pb[2];
#pragma unroll
  for (int gi = 0; gi < 2; gi++) {
    pa[gi] = *(const u16x8*)&asrc[gi * 8];
    if (bcol < NCOL) pb[gi] = *(const u16x8*)&bsrc[gi * 8];
    else { u16x8 z; for (int e = 0; e < 8; e++) z[e] = 0; pb[gi] = z; }
  }

  for (int kc = 0; kc < 10; kc++) {
    __syncthreads();
#pragma unroll
    for (int gi = 0; gi < 2; gi++) {
      int g = sg + gi;
      *(u16x8*)&At[sr * 64 + ((g ^ (sr & 7)) << 3)] = pa[gi];
      *(u16x8*)&Bt[sr * 64 + ((g ^ (sr & 7)) << 3)] = pb[gi];
    }
    if (kc < 9) {
      const unsigned short* an = asrc + (kc + 1) * 64;
      const unsigned short* bn = bsrc + (kc + 1) * 64;
#pragma unroll
      for (int gi = 0; gi < 2; gi++) {
        pa[gi] = *(const u16x8*)&an[gi * 8];
        if (bcol < NCOL) pb[gi] = *(const u16x8*)&bn[gi * 8];
      }
    }
    __syncthreads();
#pragma unroll
    for (int ks = 0; ks < 4; ks++) {
      int gk = ks * 2 + ksel;
      s16x8 bf1;
      {
        int R = wc * 32 + lr;
        bf1 = *(const s16x8*)&Bt[R * 64 + ((gk ^ (R & 7)) << 3)];
      }
#pragma unroll
      for (int a = 0; a < 2; a++) {
        int R = (wr + 2 * a) * 32 + lr;
        s16x8 af = *(const s16x8*)&At[R * 64 + ((gk ^ (R & 7)) << 3)];
        acc[a] = __builtin_amdgcn_mfma_f32_32x32x16_bf16(af, bf1, acc[a], 0, 0, 0);
      }
    }
  }

  int col = ctile + wc * 32 + lr;
  if (col < NCOL) {
#pragma unroll
    for (int a = 0; a < 2; a++) {
      int obase = otile + (wr + 2 * a) * 32 + 4 * ksel;
#pragma unroll
      for (int g2 = 0; g2 < 4; g2++) {
        u16x4 v;
        v.x = f2bf(acc[a][g2 * 4 + 0]);
        v.y = f2bf(acc[a][g2 * 4 + 1]);
        v.z = f2bf(acc[a][g2 * 4 + 2]);
        v.w = f2bf(acc[a][g2 * 4 + 3]);
        *(u16x4*)&out[(long)col * CCH + obase + g2 * 8] = v;
      }
    }
  }
}

// =====================================================================
// Kernel B: MFMA attention (unchanged from r10/r11)
// =====================================================================
__global__ __launch_bounds__(256) void attn_kernel(const unsigned short* __restrict__ proj,
                                                   const unsigned short* __restrict__ XTB,
                                                   unsigned short* __restrict__ feat,
                                                   int chunk_start) {
  int tid = threadIdx.x, wid = tid >> 6, lane = tid & 63;
  int lr = lane & 31, hf = lane >> 5;
  int rclamp = lr > 24 ? 24 : lr;
  int bid = blockIdx.x;
  int pw = bid / 10, grp = bid - pw * 10;
  int unit = grp * 4 + wid;
  int side = unit >= 20 ? 1 : 0;
  int head = unit - side * 20;
  int lpi = pw / 5, way = pw - lpi * 5;
  int pair = chunk_start + lpi;
  int b = pair / 75;
  int qcol = (50 + pair) * PP;
  int sitem0 = b * 25 + way * 5;
  int ho = head * 32;
  const unsigned short* Qp = proj;
  const unsigned short* Kp = proj + (long)NCOL * CCH;
  const unsigned short* Vp = proj + 2L * NCOL * CCH;
  unsigned short* fb = feat + (long)pw * FEAT_PER_WAY_US + head * 250 * 32;

  auto ldfrag = [&](const unsigned short* src, int col0, int ks) -> s16x8 {
    return *(const s16x8*)&src[(long)(col0 + rclamp) * CCH + ho + ks * 16 + hf * 8];
  };
  auto ldvfrag = [&](int col0, int ks) -> s16x8 {
    const unsigned short* base = Vp + (long)(col0 + ks * 16 + hf * 8) * CCH + ho + lr;
    s16x8 f;
#pragma unroll
    for (int j = 0; j < 8; j++) f[j] = (short)base[(long)j * CCH];
    return f;
  };

  s16x8 fA0, fA1, fB0, fB1, fV0, fV1;
  float scv[16];
  if (side == 0) {
    fB0 = ldfrag(Qp, qcol, 0); fB1 = ldfrag(Qp, qcol, 1);
  } else {
    fA0 = ldfrag(Kp, qcol, 0); fA1 = ldfrag(Kp, qcol, 1);
    fV0 = ldvfrag(qcol, 0);    fV1 = ldvfrag(qcol, 1);
#pragma unroll
    for (int rg = 0; rg < 16; rg++) {
      int q = (rg & 3) + 8 * (rg >> 2) + 4 * hf;
      int qc = q > 24 ? 24 : q;
      scv[rg] = bf2f(XTB[(long)(qcol + qc) * CCH + ho + lr]);
    }
  }

  for (int shot = 0; shot < 5; shot++) {
    int scol = (sitem0 + shot) * PP;
    s16x8 A0, A1, B0, B1, V0, V1;
    if (side == 0) {
      A0 = ldfrag(Kp, scol, 0); A1 = ldfrag(Kp, scol, 1);
      B0 = fB0; B1 = fB1;
      V0 = ldvfrag(scol, 0);    V1 = ldvfrag(scol, 1);
    } else {
      A0 = fA0; A1 = fA1;
      B0 = ldfrag(Qp, scol, 0); B1 = ldfrag(Qp, scol, 1);
      V0 = fV0; V1 = fV1;
    }
    f32x16 s;
#pragma unroll
    for (int e = 0; e < 16; e++) s[e] = 0.f;
    s = __builtin_amdgcn_mfma_f32_32x32x16_bf16(A0, B0, s, 0, 0, 0);
    s = __builtin_amdgcn_mfma_f32_32x32x16_bf16(A1, B1, s, 0, 0, 0);
    float pv[16];
    float mx = -1e30f;
#pragma unroll
    for (int rg = 0; rg < 16; rg++) {
      int mm = (rg & 3) + 8 * (rg >> 2) + 4 * hf;
      float v = (mm < 25) ? s[rg] : -1e30f;
      pv[rg] = v;
      mx = fmaxf(mx, v);
    }
    mx = fmaxf(mx, __shfl_xor(mx, 32));
    float sum = 0.f;
#pragma unroll
    for (int rg = 0; rg < 16; rg++) {
      float e = __expf((pv[rg] - mx) * SCALE_INV);
      pv[rg] = e;
      sum += e;
    }
    sum += __shfl_xor(sum, 32);
    float rinv = 1.f / sum;
#pragma unroll
    for (int rg = 0; rg < 16; rg++) pv[rg] *= rinv;
    union { unsigned u[4]; s16x8 v; } P0u, P1u;
    {
      float ex[8], fr[8];
#pragma unroll
      for (int r = 0; r < 8; r++) ex[r] = __shfl_xor(pv[r], 32);
#pragma unroll
      for (int j = 0; j < 4; j++) {
        fr[j]     = hf ? ex[4 + j] : pv[j];
        fr[4 + j] = hf ? pv[4 + j] : ex[j];
      }
#pragma unroll
      for (int j = 0; j < 4; j++) P0u.u[j] = cvtpk(fr[2 * j], fr[2 * j + 1]);
#pragma unroll
      for (int r = 0; r < 8; r++) ex[r] = __shfl_xor(pv[8 + r], 32);
#pragma unroll
      for (int j = 0; j < 4; j++) {
        fr[j]     = hf ? ex[4 + j] : pv[8 + j];
        fr[4 + j] = hf ? pv[12 + j] : ex[j];
      }
#pragma unroll
      for (int j = 0; j < 4; j++) P1u.u[j] = cvtpk(fr[2 * j], fr[2 * j + 1]);
    }
    f32x16 o;
#pragma unroll
    for (int e = 0; e < 16; e++) o[e] = 0.f;
    o = __builtin_amdgcn_mfma_f32_32x32x16_bf16(P0u.v, V0, o, 0, 0, 0);
    o = __builtin_amdgcn_mfma_f32_32x32x16_bf16(P1u.v, V1, o, 0, 0, 0);
    unsigned short* frow = fb + (long)((side ? 125 : 0) + shot * 25) * 32;
    const unsigned short* scb = XTB + (long)(scol + 4 * hf) * CCH + ho + lr;
#pragma unroll
    for (int i = 0; i < 8; i++) {
      int rg0 = 2 * i, rg1 = rg0 + 1;
      int qoff = (rg0 & 3) + 8 * (rg0 >> 2);
      int q0 = qoff + 4 * hf, q1 = q0 + 1;
      float sc0, sc1;
      if (side) { sc0 = scv[rg0]; sc1 = scv[rg1]; }
      else {
        sc0 = bf2f(scb[(long)qoff * CCH]);
        sc1 = bf2f(scb[(long)(qoff + 1) * CCH]);
      }
      unsigned u = cvtpk(o[rg0] + sc0, o[rg1] + sc1);
      if (q0 < 25) frow[q0 * 32 + lr] = (unsigned short)u;
      if (q1 < 25) frow[q1 * 32 + lr] = (unsigned short)(u >> 16);
    }
  }
}

// =====================================================================
// Kernel C: MFMA bf16 Gram — 1024 threads / 16 waves per (pair,way).
// Wave grid 4x4, each wave 2x2 tiles (acc 64 regs -> 4 waves/SIMD).
// Same swizzle / gload_lds dbuf staging / ones-row harvest as r11.
// =====================================================================
__global__ __launch_bounds__(1024) void gram_kernel(const unsigned short* __restrict__ feat,
                                                    const unsigned short* __restrict__ ones,
                                                    float* __restrict__ mmd,
                                                    int chunk_start) {
  __shared__ __align__(16) unsigned short tile[2][16384];
  __shared__ float sums[256], nrmsq[256], meanv[256], nrmv[256];
  __shared__ float red[48];
  int bid = blockIdx.x;
  const unsigned short* fb = feat + (long)bid * FEAT_PER_WAY_US;
  int tid = threadIdx.x;
  int w = tid >> 6, lane = tid & 63;
  int wr = w >> 2, wc = w & 3;
  int lr = lane & 31, ksel = lane >> 5;

  // staging: 2 slots per thread; slot s = (w*2+i)*64 + lane, pre-swizzled source
  const unsigned short* srcp[2];
  long stepv[2];
#pragma unroll
  for (int i = 0; i < 2; i++) {
    int s = (w * 2 + i) * 64 + lane;
    int row = s >> 3, gs = s & 7, g = gs ^ (row & 7);
    if (row < 250) {
      srcp[i] = fb + (long)((g >> 2) * 250 + row) * 32 + (g & 3) * 8;
      stepv[i] = 16000;      // advance 64 ch (2 heads) per kc
    } else {
      srcp[i] = ones + (row - 250) * 64 + g * 8;
      stepv[i] = 0;
    }
  }

  f32x16 acc[2][2];
#pragma unroll
  for (int a = 0; a < 2; a++)
#pragma unroll
    for (int b2 = 0; b2 < 2; b2++)
#pragma unroll
      for (int e = 0; e < 16; e++) acc[a][b2][e] = 0.f;

  // prologue: stage kc=0 into buf 0
#pragma unroll
  for (int i = 0; i < 2; i++)
    __builtin_amdgcn_global_load_lds((glb_u32*)srcp[i],
                                     (lds_u32*)&tile[0][(w * 2 + i) * 512], 16, 0, 0);
  __syncthreads();

  for (int kc = 0; kc < 10; kc++) {
    int cur = kc & 1;
    if (kc < 9) {
#pragma unroll
      for (int i = 0; i < 2; i++)
        __builtin_amdgcn_global_load_lds((glb_u32*)(srcp[i] + (long)(kc + 1) * stepv[i]),
                                         (lds_u32*)&tile[cur ^ 1][(w * 2 + i) * 512], 16, 0, 0);
    }
    const unsigned short* tb = tile[cur];
#pragma unroll
    for (int ks = 0; ks < 4; ks++) {
      int gk = ks * 2 + ksel;
      s16x8 af[2], bfv[2];
#pragma unroll
      for (int a = 0; a < 2; a++) {
        int R = (wr + 4 * a) * 32 + lr;
        af[a] = *(const s16x8*)&tb[R * 64 + ((gk ^ (R & 7)) << 3)];
      }
#pragma unroll
      for (int b2 = 0; b2 < 2; b2++) {
        int R = (wc + 4 * b2) * 32 + lr;
        bfv[b2] = *(const s16x8*)&tb[R * 64 + ((gk ^ (R & 7)) << 3)];
      }
#pragma unroll
      for (int a = 0; a < 2; a++)
#pragma unroll
        for (int b2 = 0; b2 < 2; b2++)
          acc[a][b2] = __builtin_amdgcn_mfma_f32_32x32x16_bf16(af[a], bfv[b2], acc[a][b2], 0, 0, 0);
    }
    __syncthreads();   // drains vmcnt (next buf landed) + lgkmcnt (reads done)
  }

  // ---- harvest row sums (col 250) and squared norms (diagonal) ----
#pragma unroll
  for (int a = 0; a < 2; a++) {
    int ti = wr + 4 * a;
#pragma unroll
    for (int b2 = 0; b2 < 2; b2++) {
      int tj = wc + 4 * b2;
      int col = tj * 32 + lr;
      if (col == 250) {
#pragma unroll
        for (int rg = 0; rg < 16; rg++) {
          int row = ti * 32 + (rg & 3) + 8 * (rg >> 2) + 4 * ksel;
          if (row < 250) sums[row] = acc[a][b2][rg];
        }
      }
      if (ti == tj) {
#pragma unroll
        for (int rg = 0; rg < 16; rg++) {
          int row = ti * 32 + (rg & 3) + 8 * (rg >> 2) + 4 * ksel;
          if (row == col && row < 250) nrmsq[row] = acc[a][b2][rg];
        }
      }
    }
  }
  __syncthreads();
  if (tid < 250) {
    float s0 = sums[tid];
    float m = s0 * (1.f / 640.f);
    meanv[tid] = m;
    nrmv[tid] = nrmsq[tid] - s0 * m;
  }
  __syncthreads();

  // ---- epilogue: d2 -> 5-term gaussian kernel -> region sums ----
  float s_ss = 0.f, s_qq = 0.f, s_x = 0.f;
#pragma unroll
  for (int a = 0; a < 2; a++) {
    int ti = wr + 4 * a;
#pragma unroll
    for (int b2 = 0; b2 < 2; b2++) {
      int tj = wc + 4 * b2;
      int col = tj * 32 + lr;
#pragma unroll
      for (int rg = 0; rg < 16; rg++) {
        int row = ti * 32 + (rg & 3) + 8 * (rg >> 2) + 4 * ksel;
        if (row < 250 && col < 250) {
          float d2 = nrmv[row] + nrmv[col] - 2.f * acc[a][b2][rg]
                   + 1280.f * meanv[row] * meanv[col];
          d2 = fmaxf(d2, 0.f);
          float e = __expf(-0.125f * d2);
          float e2 = e * e, e4 = e2 * e2, e8 = e4 * e4, e16 = e8 * e8;
          float kv = e + e2 + e4 + e8 + e16;
          bool rs = row < 125, cs = col < 125;
          if (rs && cs)        { if (row != col) s_ss += kv; }
          else if (!rs && !cs) { if (row != col) s_qq += kv; }
          else                 s_x += kv;
        }
      }
    }
  }
#pragma unroll
  for (int off = 32; off; off >>= 1) {
    s_ss += __shfl_xor(s_ss, off);
    s_qq += __shfl_xor(s_qq, off);
    s_x  += __shfl_xor(s_x, off);
  }
  if (lane == 0) { red[w * 3] = s_ss; red[w * 3 + 1] = s_qq; red[w * 3 + 2] = s_x; }
  __syncthreads();
  if (tid == 0) {
    float a = 0.f, b2 = 0.f, c = 0.f;
    for (int i = 0; i < 16; i++) { a += red[i * 3]; b2 += red[i * 3 + 1]; c += red[i * 3 + 2]; }
    mmd[(long)chunk_start * 5 + bid] = a * (1.f / 15500.f) + b2 * (1.f / 15500.f) - c * (1.f / 15625.f);
  }
}

// =====================================================================
// Kernel D: log-softmax + NLL mean
// =====================================================================
__global__ __launch_bounds__(256) void loss_kernel(const float* __restrict__ mmd,
                                                   const int* __restrict__ qy,
                                                   float* __restrict__ out) {
  __shared__ float red[256];
  int tid = threadIdx.x;
  float val = 0.f;
  if (tid < 150) {
    float l[5];
    float mx = -1e30f;
#pragma unroll
    for (int w = 0; w < 5; w++) {
      l[w] = -mmd[tid * 5 + w] * (1.0f / 12.5f);
      mx = fmaxf(mx, l[w]);
    }
    float sum = 0.f;
#pragma unroll
    for (int w = 0; w < 5; w++) sum += __expf(l[w] - mx);
    float lse = mx + logf(sum);
    int y = qy[tid];
    val = -(l[y] - lse);
  }
  red[tid] = val;
  __syncthreads();
  for (int s = 128; s > 0; s >>= 1) {
    if (tid < s) red[tid] += red[tid + s];
    __syncthreads();
  }
  if (tid == 0) out[0] = red[0] * (1.0f / 150.0f);
}

// =====================================================================
extern "C" void kernel_launch(void* const* d_in, const int* in_sizes, int n_in,
                              void* d_out, int out_size, void* d_ws, size_t ws_size,
                              hipStream_t stream) {
  (void)in_sizes; (void)n_in; (void)out_size;
  const float* sup = (const float*)d_in[0];
  const float* qry = (const float*)d_in[2];
  const int* qy = (const int*)d_in[3];
  const float* Wq = (const float*)d_in[4];
  const float* Wk = (const float*)d_in[5];
  const float* Wv = (const float*)d_in[6];
  float* ws = (float*)d_ws;
  unsigned short* XTB = (unsigned short*)(ws + XTB_OFF);
  unsigned short* WB = (unsigned short*)(ws + WB_OFF);
  unsigned short* projB = (unsigned short*)(ws + PROJB_OFF);
  float* mmd = ws + MMD_OFF;
  unsigned short* ones = (unsigned short*)(ws + ONES_OFF);
  unsigned short* feat = (unsigned short*)(ws + FEAT_OFF);
  float* out = (float*)d_out;

  long wsf = (long)(ws_size / 4);
  long avail_us = (wsf - FEAT_OFF) * 2;
  long chunkL = avail_us / FEAT_PER_PAIR_US;
  int chunk = (chunkL > 150) ? 150 : (chunkL < 1 ? 1 : (int)chunkL);

  hipLaunchKernelGGL(t_kernel, dim3(200), dim3(256), 0, stream, sup, qry, XTB);
  hipLaunchKernelGGL(w_kernel, dim3(600), dim3(256), 0, stream, Wq, Wk, Wv, WB, ones);
  hipLaunchKernelGGL(proj_kernel, dim3(40, 5, 3), dim3(512), 0, stream, WB, XTB, projB);
  for (int c0 = 0; c0 < 150; c0 += chunk) {
    int cp = (150 - c0 < chunk) ? (150 - c0) : chunk;
    hipLaunchKernelGGL(attn_kernel, dim3(cp * 50), dim3(256), 0, stream, projB, XTB, feat, c0);
    hipLaunchKernelGGL(gram_kernel, dim3(cp * 5), dim3(1024), 0, stream, feat, ones, mmd, c0);
  }
  hipLaunchKernelGGL(loss_kernel, dim3(1), dim3(256), 0, stream, mmd, qy, out);
}